// Round 1
// baseline (911.778 us; speedup 1.0000x reference)
//
#include <hip/hip_runtime.h>
#include <cmath>

#ifndef M_PI
#define M_PI 3.14159265358979323846
#endif

#define NIMG 512
#define NRHO 1024
#define NTH  512
#define NW   257            // NTH/2+1
#define PTOT (1024*512)     // n_angles * n_det

// ---------------- host-side scalar constants (pure, computed once at load) ----------------
struct Consts { double G_LA, d_rho, aR, dth, constv; };

static Consts compute_consts() {
  Consts c;
  const double beta = M_PI / 3.0;
  const double sb = sin(beta / 2.0), cb = cos(beta / 2.0);
  const double aR = sb / (1.0 + sb);
  const double am = (cb - sb) / (1.0 + sb);
  // g = nanmax(log|w| + log cos(beta/2 - arg w)), t = linspace(-pi/2, pi/2, 1000)
  double g = -1e300;
  const double start = -M_PI / 2.0, stop = M_PI / 2.0;
  const double delta = (stop - start) / 999.0;
  for (int i = 0; i < 1000; ++i) {
    double t = (i == 999) ? stop : (double)i * delta + start;
    double wre = aR * cos(t) + (1.0 - aR);
    double wim = aR * sin(t);
    double v = log(hypot(wre, wim)) + log(cos(beta / 2.0 - atan2(wim, wre)));
    if (!std::isnan(v) && v > g) g = v;
  }
  c.aR    = aR;
  c.G_LA  = g - log(am);          // g - log(a_m)
  c.d_rho = c.G_LA / 1024.0;      // exact /2^10
  // dth = th_sp_large[1] - th_sp_large[0], replicating numpy eval order
  double t1 = (-1023.0 / 2048.0) * beta * 2.0;
  double t0 = (-1024.0 / 2048.0) * beta * 2.0;
  c.dth = t1 - t0;
  c.constv = sqrt(0.5) * M_PI / 4.0 / aR / sqrt(2.0);
  return c;
}
static const Consts g_C = compute_consts();

// ---------------- device FFT helpers (in-place LDS radix-2) ----------------
__device__ __forceinline__ float2 cmulf(float2 a, float2 b) {
  return make_float2(a.x * b.x - a.y * b.y, a.x * b.y + a.y * b.x);
}
__device__ __forceinline__ double2 cmuld(double2 a, double2 b) {
  return make_double2(a.x * b.x - a.y * b.y, a.x * b.y + a.y * b.x);
}

// DIT: input bit-reversed, output natural. tw[m] = exp(-2*pi*i*m/N), m < N/2.
template<int LOG2N>
__device__ void fft_dit_f(float2* s, const float2* tw, int sign) {
  const int NH = 1 << (LOG2N - 1);
  for (int lh = 0; lh < LOG2N; ++lh) {
    __syncthreads();
    for (int b = threadIdx.x; b < NH; b += blockDim.x) {
      int pos = b & ((1 << lh) - 1);
      int i0  = ((b >> lh) << (lh + 1)) | pos;
      float2 w = tw[pos << (LOG2N - 1 - lh)];
      if (sign > 0) w.y = -w.y;
      float2 u = s[i0];
      float2 v = cmulf(s[i0 + (1 << lh)], w);
      s[i0]             = make_float2(u.x + v.x, u.y + v.y);
      s[i0 + (1 << lh)] = make_float2(u.x - v.x, u.y - v.y);
    }
  }
  __syncthreads();
}

// DIF: input natural, output bit-reversed (out[k] = s[rev(k)]).
template<int LOG2N>
__device__ void fft_dif_f(float2* s, const float2* tw, int sign) {
  const int NH = 1 << (LOG2N - 1);
  for (int lh = LOG2N - 1; lh >= 0; --lh) {
    __syncthreads();
    for (int b = threadIdx.x; b < NH; b += blockDim.x) {
      int pos = b & ((1 << lh) - 1);
      int i0  = ((b >> lh) << (lh + 1)) | pos;
      float2 w = tw[pos << (LOG2N - 1 - lh)];
      if (sign > 0) w.y = -w.y;
      float2 u = s[i0];
      float2 v = s[i0 + (1 << lh)];
      s[i0] = make_float2(u.x + v.x, u.y + v.y);
      float2 d = make_float2(u.x - v.x, u.y - v.y);
      s[i0 + (1 << lh)] = cmulf(d, w);
    }
  }
  __syncthreads();
}

// double, N=2048, forward only
__device__ void fft_dit_d2048(double2* s, const double2* tw) {
  for (int lh = 0; lh < 11; ++lh) {
    __syncthreads();
    for (int b = threadIdx.x; b < 1024; b += blockDim.x) {
      int pos = b & ((1 << lh) - 1);
      int i0  = ((b >> lh) << (lh + 1)) | pos;
      double2 w = tw[pos << (10 - lh)];
      double2 u = s[i0];
      double2 v = cmuld(s[i0 + (1 << lh)], w);
      s[i0]             = make_double2(u.x + v.x, u.y + v.y);
      s[i0 + (1 << lh)] = make_double2(u.x - v.x, u.y - v.y);
    }
  }
  __syncthreads();
}

// ---------------- zeta (complex filter) kernel, FP64 ----------------
__device__ __forceinline__ double h_val(int jj) {
  const double ctab[11] = {-216254335.0, 679543284.0, -1412947389.0, 2415881496.0,
                           -3103579086.0, 2939942400.0, -2023224114.0, 984515304.0,
                           -321455811.0, 63253516.0, -5675265.0};
  int j = -1;
  if (jj <= 10) j = jj;
  else if (jj >= 2038) j = 2048 - jj;
  if (j < 0) return 1.0;
  double c = 1.0 + ctab[j] / 958003200.0;
  if (j == 0) c = 2.0 * (c - 0.5);
  return c;
}

__global__ __launch_bounds__(256) void k_zeta(float2* __restrict__ zeta,
                                              double G_LA, double dth, double constv) {
  __shared__ double2 s[2048];    // 32 KB
  __shared__ double2 tw[1024];   // 16 KB
  const int i   = blockIdx.x;    // k_rho row, 0..1023
  const int tid = threadIdx.x;
  const double beta = M_PI / 3.0;
  for (int m = tid; m < 1024; m += 256) {
    double ang = -2.0 * M_PI * (double)m / 2048.0;
    double sv, cv; sincos(ang, &sv, &cv);
    tw[m] = make_double2(cv, sv);
  }
  const double om = 2.0 * M_PI * (double)(i - 512) / G_LA;  // omega
  // row = fftshift(h * fcosa[i]), stored bit-reversed for DIT
  for (int j = tid; j < 2048; j += 256) {
    int jj = (j + 1024) & 2047;                       // fftshift source index
    double th = ((double)(jj - 1024) / 2048.0) * beta * 2.0;
    double L  = log(cos(th));                         // <= 0
    double amp = h_val(jj) * exp(-L);                 // exp((-1)*L) part of cos^expo
    double sv, cv; sincos(-om * L, &sv, &cv);         // exp(-i*om*L)
    s[__brev((unsigned)j) >> 21] = make_double2(amp * cv, amp * sv);
  }
  fft_dit_d2048(s, tw);                               // F, natural order
  // zeta[i2][j2] = F[j2] * dth * const / b3(i2,j2)  (j2 < 256); row i==0 and col 256 zeroed
  const int i2 = (i + 512) & 1023;
  const double b3r = (4.0 + 2.0 * cos(2.0 * M_PI * (double)i2 / 1024.0)) / 6.0;
  for (int j2 = tid; j2 < NW; j2 += 256) {
    float2 z = make_float2(0.f, 0.f);
    if (i != 0 && j2 != 256) {
      double2 F = s[j2];
      double b3t = (4.0 + 2.0 * cos(2.0 * M_PI * (double)j2 / 512.0)) / 6.0;
      double sc = dth * constv / (b3r * b3t);
      z = make_float2((float)(F.x * sc), (float)(F.y * sc));
    }
    zeta[i2 * NW + j2] = z;
  }
}

// ---------------- log-polar gather index map (per span) ----------------
__global__ __launch_bounds__(256) void k_idx_lp2c(int* __restrict__ idx1, int span,
                                                  double d_rho, double aR) {
  int q = blockIdx.x * 256 + threadIdx.x;
  if (q >= NRHO * NTH) return;
  int i = q >> 9, j = q & 511;
  const double beta = M_PI / 3.0;
  double d_th = 2.0 * beta / 512.0;
  double th = (double)(j - 256) * d_th;
  double er = exp((double)(i - 1024) * d_rho);
  double t1 = er * cos(th), t2 = er * sin(th);
  double a = (double)span * beta + beta / 2.0;
  double ca = cos(a), sa = sin(a);
  double l1 = ((t1 - (1.0 - aR)) * ca - t2 * sa) / aR;
  double l2 = -(((t1 - (1.0 - aR)) * sa + t2 * ca) / aR);
  l1 = (l1 + 1.0) / 2.0 * 511.0;
  l2 = (l2 + 1.0) / 2.0 * 511.0;
  double fy = floor(l1); fy = fy < 0.0 ? 0.0 : (fy > 510.0 ? 510.0 : fy);
  double fx = floor(l2); fx = fx < 0.0 ? 0.0 : (fx > 510.0 ? 510.0 : fx);
  idx1[q] = (int)fy * 512 + (int)fx;
}

// ---------------- gather + rfft(512) along theta ----------------
__global__ __launch_bounds__(256) void k_gather_rfft(const float* __restrict__ x,
                                                     const int* __restrict__ idx1,
                                                     float2* __restrict__ bufA,
                                                     int b0, double d_rho) {
  __shared__ float2 s[512];
  __shared__ float2 tw[256];
  const int i  = blockIdx.x;        // rho index
  const int lb = blockIdx.y;        // local batch
  const int tid = threadIdx.x;
  for (int m = tid; m < 256; m += 256) {
    double ang = -2.0 * M_PI * (double)m / 512.0;
    tw[m] = make_float2((float)cos(ang), (float)sin(ang));
  }
  const float er = (float)exp((double)(i - 1024) * d_rho);   // e_rho, f32 like numpy
  const float* xb = x + (size_t)(b0 + lb) * (NIMG * NIMG);
  const int* row = idx1 + i * NTH;
  for (int j = tid; j < 512; j += 256) {
    float v = xb[row[j]] * er;
    s[__brev((unsigned)j) >> 23] = make_float2(v, 0.f);
  }
  fft_dit_f<9>(s, tw, -1);
  float2* outp = bufA + ((size_t)lb * NRHO + i) * NW;
  for (int j = tid; j < NW; j += 256) outp[j] = s[j];
}

// ---------------- fft(1024) along rho, * zeta, ifft(1024) ----------------
__global__ __launch_bounds__(256) void k_fft_rho(float2* __restrict__ bufA,
                                                 const float2* __restrict__ zeta) {
  __shared__ float2 s[1024];
  __shared__ float2 tw[512];
  const int j  = blockIdx.x;        // 0..256
  const int lb = blockIdx.y;
  const int tid = threadIdx.x;
  for (int m = tid; m < 512; m += 256) {
    double ang = -2.0 * M_PI * (double)m / 1024.0;
    tw[m] = make_float2((float)cos(ang), (float)sin(ang));
  }
  float2* col = bufA + (size_t)lb * NRHO * NW + j;
  for (int i = tid; i < 1024; i += 256)
    s[__brev((unsigned)i) >> 22] = col[(size_t)i * NW];
  fft_dit_f<10>(s, tw, -1);                 // natural-order spectrum
  for (int i = tid; i < 1024; i += 256)
    s[i] = cmulf(s[i], zeta[i * NW + j]);
  fft_dif_f<10>(s, tw, +1);                 // inverse, bit-reversed output
  const float inv = 1.0f / 1024.0f;
  for (int i = tid; i < 1024; i += 256) {
    float2 v = s[__brev((unsigned)i) >> 22];
    col[(size_t)i * NW] = make_float2(v.x * inv, v.y * inv);
  }
}

// ---------------- Hermitian irfft(512) along theta -> gk ----------------
__global__ __launch_bounds__(256) void k_irfft_th(const float2* __restrict__ bufA,
                                                  float* __restrict__ gk) {
  __shared__ float2 s[512];
  __shared__ float2 tw[256];
  const int i  = blockIdx.x;
  const int lb = blockIdx.y;
  const int tid = threadIdx.x;
  for (int m = tid; m < 256; m += 256) {
    double ang = -2.0 * M_PI * (double)m / 512.0;
    tw[m] = make_float2((float)cos(ang), (float)sin(ang));
  }
  const float2* row = bufA + ((size_t)lb * NRHO + i) * NW;
  for (int j = tid; j < 512; j += 256) {
    float2 v;
    if (j == 0)        { float2 t = row[0];       v = make_float2(t.x, 0.f); }   // pocketfft: imag ignored
    else if (j == 256) { float2 t = row[256];     v = make_float2(t.x, 0.f); }
    else if (j < 256)  { v = row[j]; }
    else               { float2 t = row[512 - j]; v = make_float2(t.x, -t.y); }  // Hermitian
    s[j] = v;                                     // natural order input for DIF
  }
  fft_dif_f<9>(s, tw, +1);
  float* o = gk + ((size_t)lb * NRHO + i) * NTH;
  const float inv = 1.0f / 512.0f;
  for (int j = tid; j < 512; j += 256)
    o[j] = s[__brev((unsigned)j) >> 23].x * inv;
}

// ---------------- resample back to (angle, det) + accumulate ----------------
__global__ __launch_bounds__(256) void k_scatter(const float* __restrict__ gk,
                                                 float* __restrict__ out,
                                                 int span, int b0, int chunk,
                                                 double d_rho, double aR) {
  int p = blockIdx.x * 256 + threadIdx.x;
  if (p >= PTOT) return;
  const int t = p >> 9;       // angle index
  const int d = p & 511;      // det index
  const double beta = M_PI / 3.0;
  double th0 = (double)t * M_PI / 1024.0 - beta / 2.0;
  bool insp = (th0 >= (double)span * beta - beta / 2.0) &&
              (th0 <  (double)span * beta + beta / 2.0);
  int idx = 0;
  if (insp) {
    double th00 = th0 - (double)span * beta;
    double d_th = 2.0 * beta / 512.0;
    double th_lp0 = -256.0 * d_th, th_lpL = 255.0 * d_th;
    double p1 = (th00 - th_lp0) / (th_lpL - th_lp0) * 511.0;
    double s0v = (d == 511) ? 1.0 : (double)d * (2.0 / 511.0) - 1.0;   // linspace(-1,1,512)
    double p2 = log(s0v * aR + (1.0 - aR) * cos(th00));                // arg > 0 in-span
    double rho0 = -1024.0 * d_rho, rhoL = -1.0 * d_rho;
    p2 = (p2 - rho0) / (rhoL - rho0) * 1023.0;
    double fy = floor(p2); fy = fy < 0.0 ? 0.0 : (fy > 1022.0 ? 1022.0 : fy);
    double fx = floor(p1); fx = fx < 0.0 ? 0.0 : (fx > 510.0 ? 510.0 : fx);
    idx = (int)fy * 512 + (int)fx;
  }
  for (int lb = 0; lb < chunk; ++lb) {
    size_t o = (size_t)(b0 + lb) * PTOT + p;
    if (span == 0)      out[o] = insp ? gk[(size_t)lb * (NRHO * NTH) + idx] : 0.0f;
    else if (insp)      out[o] += gk[(size_t)lb * (NRHO * NTH) + idx];
  }
}

// ---------------- launch ----------------
extern "C" void kernel_launch(void* const* d_in, const int* in_sizes, int n_in,
                              void* d_out, int out_size, void* d_ws, size_t ws_size,
                              hipStream_t stream) {
  (void)n_in; (void)out_size;
  const float* x = (const float*)d_in[0];
  float* out = (float*)d_out;
  const int batch = in_sizes[0] / (NIMG * NIMG);

  // workspace carve-up
  const size_t zeta_b = (size_t)NRHO * NW * sizeof(float2);   // 2,105,344
  const size_t idx_b  = (size_t)NRHO * NTH * sizeof(int);     // 2,097,152
  const size_t per_b  = (size_t)NRHO * NW * sizeof(float2)    // bufA row-spectra
                      + (size_t)NRHO * NTH * sizeof(float);   // gk
  int chunk = batch;
  while (chunk > 1 && zeta_b + idx_b + (size_t)chunk * per_b > ws_size) chunk >>= 1;

  char* ws = (char*)d_ws;
  float2* zeta = (float2*)ws;  ws += zeta_b;
  int*    idx1 = (int*)ws;     ws += idx_b;
  float2* bufA = (float2*)ws;  ws += (size_t)chunk * NRHO * NW * sizeof(float2);
  float*  gk   = (float*)ws;

  k_zeta<<<dim3(1024), dim3(256), 0, stream>>>(zeta, g_C.G_LA, g_C.dth, g_C.constv);

  for (int k = 0; k < 3; ++k) {
    k_idx_lp2c<<<dim3((NRHO * NTH) / 256), dim3(256), 0, stream>>>(idx1, k, g_C.d_rho, g_C.aR);
    for (int b0 = 0; b0 < batch; b0 += chunk) {
      int c = (b0 + chunk <= batch) ? chunk : (batch - b0);
      k_gather_rfft<<<dim3(NRHO, c), dim3(256), 0, stream>>>(x, idx1, bufA, b0, g_C.d_rho);
      k_fft_rho   <<<dim3(NW, c),   dim3(256), 0, stream>>>(bufA, zeta);
      k_irfft_th  <<<dim3(NRHO, c), dim3(256), 0, stream>>>(bufA, gk);
      k_scatter   <<<dim3(PTOT / 256), dim3(256), 0, stream>>>(gk, out, k, b0, c,
                                                               g_C.d_rho, g_C.aR);
    }
  }
}

// Round 2
// 796.666 us; speedup vs baseline: 1.1445x; 1.1445x over previous
//
#include <hip/hip_runtime.h>
#include <cmath>

#ifndef M_PI
#define M_PI 3.14159265358979323846
#endif

#define NIMG 512
#define NRHO 1024
#define NTH  512
#define NW   257            // NTH/2+1
#define NWP  264            // padded row stride (264*8 = 2112 bytes = 33 cache lines)
#define CSTR 1061           // LDS column stride in float2 (odd -> bank decorrelation)
#define PTOT (1024*512)     // n_angles * n_det

// ---------------- host-side scalar constants (pure, computed once at load) ----------------
struct Consts { double G_LA, d_rho, aR, dth, constv; };

static Consts compute_consts() {
  Consts c;
  const double beta = M_PI / 3.0;
  const double sb = sin(beta / 2.0), cb = cos(beta / 2.0);
  const double aR = sb / (1.0 + sb);
  const double am = (cb - sb) / (1.0 + sb);
  double g = -1e300;
  const double start = -M_PI / 2.0, stop = M_PI / 2.0;
  const double delta = (stop - start) / 999.0;
  for (int i = 0; i < 1000; ++i) {
    double t = (i == 999) ? stop : (double)i * delta + start;
    double wre = aR * cos(t) + (1.0 - aR);
    double wim = aR * sin(t);
    double v = log(hypot(wre, wim)) + log(cos(beta / 2.0 - atan2(wim, wre)));
    if (!std::isnan(v) && v > g) g = v;
  }
  c.aR    = aR;
  c.G_LA  = g - log(am);
  c.d_rho = c.G_LA / 1024.0;
  double t1 = (-1023.0 / 2048.0) * beta * 2.0;
  double t0 = (-1024.0 / 2048.0) * beta * 2.0;
  c.dth = t1 - t0;
  c.constv = sqrt(0.5) * M_PI / 4.0 / aR / sqrt(2.0);
  return c;
}
static const Consts g_C = compute_consts();

// ---------------- device complex helpers ----------------
__device__ __forceinline__ float2 cmulf(float2 a, float2 b) {
  return make_float2(a.x * b.x - a.y * b.y, a.x * b.y + a.y * b.x);
}
__device__ __forceinline__ double2 cmuld(double2 a, double2 b) {
  return make_double2(a.x * b.x - a.y * b.y, a.x * b.y + a.y * b.x);
}

// DIT: input bit-reversed, output natural. tw[m] = exp(-2*pi*i*m/N), m < N/2.
template<int LOG2N>
__device__ void fft_dit_f(float2* s, const float2* tw, int sign) {
  const int NH = 1 << (LOG2N - 1);
  for (int lh = 0; lh < LOG2N; ++lh) {
    __syncthreads();
    for (int b = threadIdx.x; b < NH; b += blockDim.x) {
      int pos = b & ((1 << lh) - 1);
      int i0  = ((b >> lh) << (lh + 1)) | pos;
      float2 w = tw[pos << (LOG2N - 1 - lh)];
      if (sign > 0) w.y = -w.y;
      float2 u = s[i0];
      float2 v = cmulf(s[i0 + (1 << lh)], w);
      s[i0]             = make_float2(u.x + v.x, u.y + v.y);
      s[i0 + (1 << lh)] = make_float2(u.x - v.x, u.y - v.y);
    }
  }
  __syncthreads();
}

// DIF: input natural, output bit-reversed.
template<int LOG2N>
__device__ void fft_dif_f(float2* s, const float2* tw, int sign) {
  const int NH = 1 << (LOG2N - 1);
  for (int lh = LOG2N - 1; lh >= 0; --lh) {
    __syncthreads();
    for (int b = threadIdx.x; b < NH; b += blockDim.x) {
      int pos = b & ((1 << lh) - 1);
      int i0  = ((b >> lh) << (lh + 1)) | pos;
      float2 w = tw[pos << (LOG2N - 1 - lh)];
      if (sign > 0) w.y = -w.y;
      float2 u = s[i0];
      float2 v = s[i0 + (1 << lh)];
      s[i0] = make_float2(u.x + v.x, u.y + v.y);
      float2 d = make_float2(u.x - v.x, u.y - v.y);
      s[i0 + (1 << lh)] = cmulf(d, w);
    }
  }
  __syncthreads();
}

// double, N=2048, forward only
__device__ void fft_dit_d2048(double2* s, const double2* tw) {
  for (int lh = 0; lh < 11; ++lh) {
    __syncthreads();
    for (int b = threadIdx.x; b < 1024; b += blockDim.x) {
      int pos = b & ((1 << lh) - 1);
      int i0  = ((b >> lh) << (lh + 1)) | pos;
      double2 w = tw[pos << (10 - lh)];
      double2 u = s[i0];
      double2 v = cmuld(s[i0 + (1 << lh)], w);
      s[i0]             = make_double2(u.x + v.x, u.y + v.y);
      s[i0 + (1 << lh)] = make_double2(u.x - v.x, u.y - v.y);
    }
  }
  __syncthreads();
}

// ---------------- zeta (complex filter) kernel, FP64 ----------------
// Output: rows stored in BIT-REVERSED rho order, padded stride NWP, scaled by
// const*dth/b3 * (1/1024)  (the rho-inverse-FFT normalization folded in).
__device__ __forceinline__ double h_val(int jj) {
  const double ctab[11] = {-216254335.0, 679543284.0, -1412947389.0, 2415881496.0,
                           -3103579086.0, 2939942400.0, -2023224114.0, 984515304.0,
                           -321455811.0, 63253516.0, -5675265.0};
  int j = -1;
  if (jj <= 10) j = jj;
  else if (jj >= 2038) j = 2048 - jj;
  if (j < 0) return 1.0;
  double c = 1.0 + ctab[j] / 958003200.0;
  if (j == 0) c = 2.0 * (c - 0.5);
  return c;
}

__global__ __launch_bounds__(256) void k_zeta(float2* __restrict__ zeta_br,
                                              double G_LA, double dth, double constv) {
  __shared__ double2 s[2048];    // 32 KB
  __shared__ double2 tw[1024];   // 16 KB
  const int i   = blockIdx.x;    // k_rho row, 0..1023
  const int tid = threadIdx.x;
  const double beta = M_PI / 3.0;
  for (int m = tid; m < 1024; m += 256) {
    double ang = -2.0 * M_PI * (double)m / 2048.0;
    double sv, cv; sincos(ang, &sv, &cv);
    tw[m] = make_double2(cv, sv);
  }
  const double om = 2.0 * M_PI * (double)(i - 512) / G_LA;
  for (int j = tid; j < 2048; j += 256) {
    int jj = (j + 1024) & 2047;                       // fftshift source index
    double th = ((double)(jj - 1024) / 2048.0) * beta * 2.0;
    double L  = log(cos(th));
    double amp = h_val(jj) * exp(-L);
    double sv, cv; sincos(-om * L, &sv, &cv);
    s[__brev((unsigned)j) >> 21] = make_double2(amp * cv, amp * sv);
  }
  fft_dit_d2048(s, tw);
  const int i2 = (i + 512) & 1023;                    // fftshifted row
  const int ibr = __brev((unsigned)i2) >> 22;         // bit-reversed storage row
  const double b3r = (4.0 + 2.0 * cos(2.0 * M_PI * (double)i2 / 1024.0)) / 6.0;
  for (int j2 = tid; j2 < NWP; j2 += 256) {
    float2 z = make_float2(0.f, 0.f);
    if (i != 0 && j2 < 256) {
      double2 F = s[j2];
      double b3t = (4.0 + 2.0 * cos(2.0 * M_PI * (double)j2 / 512.0)) / 6.0;
      double sc = dth * constv / (b3r * b3t) * (1.0 / 1024.0);
      z = make_float2((float)(F.x * sc), (float)(F.y * sc));
    }
    zeta_br[ibr * NWP + j2] = z;
  }
}

// ---------------- log-polar gather index map (per span) ----------------
__global__ __launch_bounds__(256) void k_idx_lp2c(int* __restrict__ idx1, int span,
                                                  double d_rho, double aR) {
  int q = blockIdx.x * 256 + threadIdx.x;
  if (q >= NRHO * NTH) return;
  int i = q >> 9, j = q & 511;
  const double beta = M_PI / 3.0;
  double d_th = 2.0 * beta / 512.0;
  double th = (double)(j - 256) * d_th;
  double er = exp((double)(i - 1024) * d_rho);
  double t1 = er * cos(th), t2 = er * sin(th);
  double a = (double)span * beta + beta / 2.0;
  double ca = cos(a), sa = sin(a);
  double l1 = ((t1 - (1.0 - aR)) * ca - t2 * sa) / aR;
  double l2 = -(((t1 - (1.0 - aR)) * sa + t2 * ca) / aR);
  l1 = (l1 + 1.0) / 2.0 * 511.0;
  l2 = (l2 + 1.0) / 2.0 * 511.0;
  double fy = floor(l1); fy = fy < 0.0 ? 0.0 : (fy > 510.0 ? 510.0 : fy);
  double fx = floor(l2); fx = fx < 0.0 ? 0.0 : (fx > 510.0 ? 510.0 : fx);
  idx1[q] = (int)fy * 512 + (int)fx;
}

// ---------------- gather + rfft(512) along theta ----------------
__global__ __launch_bounds__(256) void k_gather_rfft(const float* __restrict__ x,
                                                     const int* __restrict__ idx1,
                                                     float2* __restrict__ bufA,
                                                     int b0, double d_rho) {
  __shared__ float2 s[512];
  __shared__ float2 tw[256];
  const int i  = blockIdx.x;        // rho index
  const int lb = blockIdx.y;        // local batch
  const int tid = threadIdx.x;
  for (int m = tid; m < 256; m += 256) {
    double ang = -2.0 * M_PI * (double)m / 512.0;
    tw[m] = make_float2((float)cos(ang), (float)sin(ang));
  }
  const float er = (float)exp((double)(i - 1024) * d_rho);
  const float* xb = x + (size_t)(b0 + lb) * (NIMG * NIMG);
  const int* row = idx1 + i * NTH;
  for (int j = tid; j < 512; j += 256) {
    float v = xb[row[j]] * er;
    s[__brev((unsigned)j) >> 23] = make_float2(v, 0.f);
  }
  fft_dit_f<9>(s, tw, -1);
  float2* outp = bufA + ((size_t)lb * NRHO + i) * NWP;
  for (int j = tid; j < NWP; j += 256)
    outp[j] = (j < NW) ? s[j] : make_float2(0.f, 0.f);   // zero the pad columns
}

// ---------------- fft(1024) along rho, * zeta, ifft(1024) — 8 columns/block ----------------
__global__ __launch_bounds__(256) void k_fft_rho(float2* __restrict__ bufA,
                                                 const float2* __restrict__ zeta_br) {
  __shared__ float2 s[8 * CSTR];    // ~67.9 KB
  __shared__ float2 tw[512];        // 4 KB
  const int j0  = blockIdx.x * 8;   // first column of this tile (0..256)
  const int lb  = blockIdx.y;
  const int tid = threadIdx.x;
  for (int m = tid; m < 512; m += 256) {
    double ang = -2.0 * M_PI * (double)m / 1024.0;
    tw[m] = make_float2((float)cos(ang), (float)sin(ang));
  }
  float2* base = bufA + (size_t)lb * NRHO * NWP + j0;
  // coalesced load: 8 consecutive lanes read 64 contiguous bytes per row
  {
    int col = tid & 7, i = tid >> 3;
    for (int it = 0; it < 32; ++it, i += 32)
      s[col * CSTR + i] = base[(size_t)i * NWP + col];
  }
  __syncthreads();
  // forward DIF (natural in -> bit-reversed out), 8 columns concurrently
  for (int lh = 9; lh >= 0; --lh) {
    for (int q = tid; q < 4096; q += 256) {
      int col = q >> 9, b = q & 511;
      int pos = b & ((1 << lh) - 1);
      int i0  = ((b >> lh) << (lh + 1)) | pos;
      float2* sc = s + col * CSTR;
      float2 w = tw[pos << (9 - lh)];
      float2 u = sc[i0];
      float2 v = sc[i0 + (1 << lh)];
      sc[i0] = make_float2(u.x + v.x, u.y + v.y);
      float2 d = make_float2(u.x - v.x, u.y - v.y);
      sc[i0 + (1 << lh)] = cmulf(d, w);
    }
    __syncthreads();
  }
  // pointwise * zeta (zeta rows pre-bit-reversed, 1/1024 folded in)
  for (int q = tid; q < 8192; q += 256) {
    int col = q & 7, p = q >> 3;
    s[col * CSTR + p] = cmulf(s[col * CSTR + p], zeta_br[p * NWP + j0 + col]);
  }
  __syncthreads();
  // inverse DIT (bit-reversed in -> natural out)
  for (int lh = 0; lh < 10; ++lh) {
    for (int q = tid; q < 4096; q += 256) {
      int col = q >> 9, b = q & 511;
      int pos = b & ((1 << lh) - 1);
      int i0  = ((b >> lh) << (lh + 1)) | pos;
      float2* sc = s + col * CSTR;
      float2 w = tw[pos << (9 - lh)]; w.y = -w.y;
      float2 u = sc[i0];
      float2 v = cmulf(sc[i0 + (1 << lh)], w);
      sc[i0]             = make_float2(u.x + v.x, u.y + v.y);
      sc[i0 + (1 << lh)] = make_float2(u.x - v.x, u.y - v.y);
    }
    __syncthreads();
  }
  // coalesced store, natural order
  {
    int col = tid & 7, i = tid >> 3;
    for (int it = 0; it < 32; ++it, i += 32)
      base[(size_t)i * NWP + col] = s[col * CSTR + i];
  }
}

// ---------------- Hermitian irfft(512) along theta -> gk ----------------
__global__ __launch_bounds__(256) void k_irfft_th(const float2* __restrict__ bufA,
                                                  float* __restrict__ gk) {
  __shared__ float2 s[512];
  __shared__ float2 tw[256];
  const int i  = blockIdx.x;
  const int lb = blockIdx.y;
  const int tid = threadIdx.x;
  for (int m = tid; m < 256; m += 256) {
    double ang = -2.0 * M_PI * (double)m / 512.0;
    tw[m] = make_float2((float)cos(ang), (float)sin(ang));
  }
  const float2* row = bufA + ((size_t)lb * NRHO + i) * NWP;
  for (int j = tid; j < 512; j += 256) {
    float2 v;
    if (j == 0)        { float2 t = row[0];       v = make_float2(t.x, 0.f); }
    else if (j == 256) { float2 t = row[256];     v = make_float2(t.x, 0.f); }
    else if (j < 256)  { v = row[j]; }
    else               { float2 t = row[512 - j]; v = make_float2(t.x, -t.y); }
    s[j] = v;
  }
  fft_dif_f<9>(s, tw, +1);
  float* o = gk + ((size_t)lb * NRHO + i) * NTH;
  const float inv = 1.0f / 512.0f;
  for (int j = tid; j < 512; j += 256)
    o[j] = s[__brev((unsigned)j) >> 23].x * inv;
}

// ---------------- resample back to (angle, det) ----------------
// Spans partition the angle range exactly -> pure store, no RMW, no zero-fill.
__global__ __launch_bounds__(256) void k_scatter(const float* __restrict__ gk,
                                                 float* __restrict__ out,
                                                 int span, int b0, int chunk,
                                                 double d_rho, double aR) {
  int p = blockIdx.x * 256 + threadIdx.x;
  if (p >= PTOT) return;
  const int t = p >> 9;       // angle index
  const int d = p & 511;      // det index
  const double beta = M_PI / 3.0;
  double th0 = (double)t * M_PI / 1024.0 - beta / 2.0;
  bool insp = (th0 >= (double)span * beta - beta / 2.0) &&
              (th0 <  (double)span * beta + beta / 2.0);
  if (!insp) return;
  double th00 = th0 - (double)span * beta;
  double d_th = 2.0 * beta / 512.0;
  double th_lp0 = -256.0 * d_th, th_lpL = 255.0 * d_th;
  double p1 = (th00 - th_lp0) / (th_lpL - th_lp0) * 511.0;
  double s0v = (d == 511) ? 1.0 : (double)d * (2.0 / 511.0) - 1.0;
  double p2 = log(s0v * aR + (1.0 - aR) * cos(th00));
  double rho0 = -1024.0 * d_rho, rhoL = -1.0 * d_rho;
  p2 = (p2 - rho0) / (rhoL - rho0) * 1023.0;
  double fy = floor(p2); fy = fy < 0.0 ? 0.0 : (fy > 1022.0 ? 1022.0 : fy);
  double fx = floor(p1); fx = fx < 0.0 ? 0.0 : (fx > 510.0 ? 510.0 : fx);
  int idx = (int)fy * 512 + (int)fx;
  for (int lb = 0; lb < chunk; ++lb)
    out[(size_t)(b0 + lb) * PTOT + p] = gk[(size_t)lb * (NRHO * NTH) + idx];
}

// ---------------- launch ----------------
extern "C" void kernel_launch(void* const* d_in, const int* in_sizes, int n_in,
                              void* d_out, int out_size, void* d_ws, size_t ws_size,
                              hipStream_t stream) {
  (void)n_in; (void)out_size;
  const float* x = (const float*)d_in[0];
  float* out = (float*)d_out;
  const int batch = in_sizes[0] / (NIMG * NIMG);

  const size_t zeta_b = (size_t)NRHO * NWP * sizeof(float2);  // 2,162,688
  const size_t idx_b  = (size_t)NRHO * NTH * sizeof(int);     // 2,097,152
  const size_t per_b  = (size_t)NRHO * NWP * sizeof(float2)   // bufA (padded)
                      + (size_t)NRHO * NTH * sizeof(float);   // gk
  int chunk = batch;
  while (chunk > 1 && zeta_b + idx_b + (size_t)chunk * per_b > ws_size) chunk >>= 1;

  char* ws = (char*)d_ws;
  float2* zeta = (float2*)ws;  ws += zeta_b;
  int*    idx1 = (int*)ws;     ws += idx_b;
  float2* bufA = (float2*)ws;  ws += (size_t)chunk * NRHO * NWP * sizeof(float2);
  float*  gk   = (float*)ws;

  k_zeta<<<dim3(1024), dim3(256), 0, stream>>>(zeta, g_C.G_LA, g_C.dth, g_C.constv);

  for (int k = 0; k < 3; ++k) {
    k_idx_lp2c<<<dim3((NRHO * NTH) / 256), dim3(256), 0, stream>>>(idx1, k, g_C.d_rho, g_C.aR);
    for (int b0 = 0; b0 < batch; b0 += chunk) {
      int c = (b0 + chunk <= batch) ? chunk : (batch - b0);
      k_gather_rfft<<<dim3(NRHO, c), dim3(256), 0, stream>>>(x, idx1, bufA, b0, g_C.d_rho);
      k_fft_rho   <<<dim3(NWP / 8, c), dim3(256), 0, stream>>>(bufA, zeta);
      k_irfft_th  <<<dim3(NRHO, c), dim3(256), 0, stream>>>(bufA, gk);
      k_scatter   <<<dim3(PTOT / 256), dim3(256), 0, stream>>>(gk, out, k, b0, c,
                                                               g_C.d_rho, g_C.aR);
    }
  }
}

// Round 3
// 510.645 us; speedup vs baseline: 1.7855x; 1.5601x over previous
//
#include <hip/hip_runtime.h>
#include <cmath>

#ifndef M_PI
#define M_PI 3.14159265358979323846
#endif

#define NIMG 512
#define NRHO 1024
#define NTH  512
#define ZROWS 256           // theta bins kept (bin 256 is zeroed by zeta col -> dropped)
#define S8   516            // LDS row stride (float2) for 8-row kernels
#define PTOT (1024*512)     // n_angles * n_det

// ---------------- host-side scalar constants ----------------
struct Consts { double G_LA, d_rho, aR, dth, constv; };

static Consts compute_consts() {
  Consts c;
  const double beta = M_PI / 3.0;
  const double sb = sin(beta / 2.0), cb = cos(beta / 2.0);
  const double aR = sb / (1.0 + sb);
  const double am = (cb - sb) / (1.0 + sb);
  double g = -1e300;
  const double start = -M_PI / 2.0, stop = M_PI / 2.0;
  const double delta = (stop - start) / 999.0;
  for (int i = 0; i < 1000; ++i) {
    double t = (i == 999) ? stop : (double)i * delta + start;
    double wre = aR * cos(t) + (1.0 - aR);
    double wim = aR * sin(t);
    double v = log(hypot(wre, wim)) + log(cos(beta / 2.0 - atan2(wim, wre)));
    if (!std::isnan(v) && v > g) g = v;
  }
  c.aR    = aR;
  c.G_LA  = g - log(am);
  c.d_rho = c.G_LA / 1024.0;
  double t1 = (-1023.0 / 2048.0) * beta * 2.0;
  double t0 = (-1024.0 / 2048.0) * beta * 2.0;
  c.dth = t1 - t0;
  c.constv = sqrt(0.5) * M_PI / 4.0 / aR / sqrt(2.0);
  return c;
}
static const Consts g_C = compute_consts();

// ---------------- device helpers ----------------
__device__ __forceinline__ float2 cmulf(float2 a, float2 b) {
  return make_float2(a.x * b.x - a.y * b.y, a.x * b.y + a.y * b.x);
}
__device__ __forceinline__ float2 cmulcf(float2 a, float2 w) {   // a * conj(w)
  return make_float2(a.x * w.x + a.y * w.y, a.y * w.x - a.x * w.y);
}
__device__ __forceinline__ int dr4_10(int v) {                    // reverse 5 base-4 digits
  int r = 0;
  #pragma unroll
  for (int k = 0; k < 5; ++k) { r = (r << 2) | (v & 3); v >>= 2; }
  return r;
}
__device__ __forceinline__ double h_val(int jj) {
  const double ctab[11] = {-216254335.0, 679543284.0, -1412947389.0, 2415881496.0,
                           -3103579086.0, 2939942400.0, -2023224114.0, 984515304.0,
                           -321455811.0, 63253516.0, -5675265.0};
  int j = -1;
  if (jj <= 10) j = jj;
  else if (jj >= 2038) j = 2048 - jj;
  if (j < 0) return 1.0;
  double c = 1.0 + ctab[j] / 958003200.0;
  if (j == 0) c = 2.0 * (c - 0.5);
  return c;
}

// ---------------- precompute: L/amp tables + fp32 twiddle tables ----------------
__global__ __launch_bounds__(256) void k_pre(double* __restrict__ Ltab,
                                             double* __restrict__ amp,
                                             float2* __restrict__ tw1024f,
                                             float2* __restrict__ tw2048f) {
  int id = blockIdx.x * 256 + threadIdx.x;
  const double beta = M_PI / 3.0;
  if (id < 2048) {
    double th = ((double)(id - 1024) / 2048.0) * beta * 2.0;
    double L = log(cos(th));
    Ltab[id] = L;
    amp[id]  = h_val(id) * exp(-L);
  }
  if (id < 1024) {
    double a1 = -2.0 * M_PI * (double)id / 1024.0;
    double a2 = -2.0 * M_PI * (double)id / 2048.0;
    double s1, c1, s2, c2;
    sincos(a1, &s1, &c1); sincos(a2, &s2, &c2);
    tw1024f[id] = make_float2((float)c1, (float)s1);
    tw2048f[id] = make_float2((float)c2, (float)s2);
  }
}

// ---------------- zeta: fp32 2048-pt FFT per rho-frequency row ----------------
// Output layout: zetaT[j][p], j<256 theta bin, p = base-4-digit-reversed rho freq.
// Includes const*dth/b3 and both inverse-FFT normalizations (1/1024/512).
__global__ __launch_bounds__(256) void k_zeta(const double* __restrict__ Ltab,
                                              const double* __restrict__ amp,
                                              const float2* __restrict__ tw2048f,
                                              float2* __restrict__ zetaT,
                                              double G_LA, double dth, double constv) {
  __shared__ float2 s[2048];     // 16 KB
  __shared__ float2 twl[1024];   // 8 KB
  const int i   = blockIdx.x;    // k_rho row 0..1023
  const int tid = threadIdx.x;
  {
    const float4* tp = (const float4*)tw2048f;
    float4* lp = (float4*)twl;
    for (int e = tid; e < 512; e += 256) lp[e] = tp[e];
  }
  const double om = 2.0 * M_PI * (double)(i - 512) / G_LA;
  const double INV2PI = 1.0 / (2.0 * M_PI);
  for (int j = tid; j < 2048; j += 256) {
    int jj = (j + 1024) & 2047;                   // fftshift source
    double ph = -om * Ltab[jj] * INV2PI;
    ph -= floor(ph);
    float ang = (float)ph * 6.28318530717958647f;
    float sv, cv; __sincosf(ang, &sv, &cv);
    float a = (float)amp[jj];
    s[__brev((unsigned)j) >> 21] = make_float2(a * cv, a * sv);
  }
  for (int lh = 0; lh < 11; ++lh) {
    __syncthreads();
    for (int e = tid; e < 1024; e += 256) {
      int pos = e & ((1 << lh) - 1);
      int ia  = ((e >> lh) << (lh + 1)) | pos;
      float2 w = twl[pos << (10 - lh)];
      float2 u = s[ia];
      float2 v = cmulf(s[ia + (1 << lh)], w);
      s[ia]             = make_float2(u.x + v.x, u.y + v.y);
      s[ia + (1 << lh)] = make_float2(u.x - v.x, u.y - v.y);
    }
  }
  __syncthreads();
  const int i2 = (i + 512) & 1023;
  const int p  = dr4_10(i2);
  const double b3r = (4.0 + 2.0 * cos(2.0 * M_PI * (double)i2 / 1024.0)) / 6.0;
  if (tid < 256) {
    int j2 = tid;
    float2 z = make_float2(0.f, 0.f);
    if (i != 0) {
      float2 F = s[j2];
      double b3t = (4.0 + 2.0 * cos(2.0 * M_PI * (double)j2 / 512.0)) / 6.0;
      double sc = dth * constv / (b3r * b3t) * (1.0 / (1024.0 * 512.0));
      z = make_float2((float)((double)F.x * sc), (float)((double)F.y * sc));
    }
    zetaT[(size_t)j2 * 1024 + p] = z;
  }
}

// ---------------- log-polar gather index map (per span) ----------------
__global__ __launch_bounds__(256) void k_idx_lp2c(int* __restrict__ idx1, int span,
                                                  double d_rho, double aR) {
  int q = blockIdx.x * 256 + threadIdx.x;
  if (q >= NRHO * NTH) return;
  int i = q >> 9, j = q & 511;
  const double beta = M_PI / 3.0;
  double d_th = 2.0 * beta / 512.0;
  double th = (double)(j - 256) * d_th;
  double er = exp((double)(i - 1024) * d_rho);
  double t1 = er * cos(th), t2 = er * sin(th);
  double a = (double)span * beta + beta / 2.0;
  double ca = cos(a), sa = sin(a);
  double l1 = ((t1 - (1.0 - aR)) * ca - t2 * sa) / aR;
  double l2 = -(((t1 - (1.0 - aR)) * sa + t2 * ca) / aR);
  l1 = (l1 + 1.0) / 2.0 * 511.0;
  l2 = (l2 + 1.0) / 2.0 * 511.0;
  double fy = floor(l1); fy = fy < 0.0 ? 0.0 : (fy > 510.0 ? 510.0 : fy);
  double fx = floor(l2); fx = fx < 0.0 ? 0.0 : (fx > 510.0 ? 510.0 : fx);
  idx1[q] = (int)fy * 512 + (int)fx;
}

// ---------------- gather + rfft(512) along theta, 8 rho-rows/block, write transposed ----------------
__global__ __launch_bounds__(256) void k_gather_rfft(const float* __restrict__ x,
                                                     const int* __restrict__ idx1,
                                                     const float2* __restrict__ tw1024f,
                                                     float2* __restrict__ T,
                                                     int b0, double d_rho) {
  __shared__ float2 s[8][S8];    // 33 KB
  __shared__ float2 twl[256];
  __shared__ float ers[8];
  const int i0  = blockIdx.x * 8;
  const int lb  = blockIdx.y;
  const int tid = threadIdx.x;
  if (tid < 256) twl[tid] = tw1024f[2 * tid];        // exp(-2pi i m/512)
  if (tid < 8)   ers[tid] = (float)exp((double)(i0 + tid - 1024) * d_rho);
  __syncthreads();
  const float* xb = x + (size_t)(b0 + lb) * (NIMG * NIMG);
  for (int e = tid; e < 4096; e += 256) {
    int r = e >> 9, j = e & 511;
    float v = xb[idx1[(i0 + r) * 512 + j]] * ers[r];
    s[r][__brev((unsigned)j) >> 23] = make_float2(v, 0.f);
  }
  for (int lh = 0; lh < 9; ++lh) {
    __syncthreads();
    for (int e = tid; e < 2048; e += 256) {
      int r = e >> 8, b = e & 255;
      int pos = b & ((1 << lh) - 1);
      int ia  = ((b >> lh) << (lh + 1)) | pos;
      float2 w = twl[pos << (8 - lh)];
      float2* sr = s[r];
      float2 u = sr[ia];
      float2 v = cmulf(sr[ia + (1 << lh)], w);
      sr[ia]             = make_float2(u.x + v.x, u.y + v.y);
      sr[ia + (1 << lh)] = make_float2(u.x - v.x, u.y - v.y);
    }
  }
  __syncthreads();
  float2* Tb = T + (size_t)lb * (ZROWS * NRHO);
  for (int e = tid; e < 2048; e += 256) {              // j<256, r<8: 64B segments
    int j = e >> 3, r = e & 7;
    Tb[(size_t)j * NRHO + i0 + r] = s[r][j];
  }
}

// ---------------- rho: fft1024 * zeta * ifft1024, radix-4, one theta-bin per block ----------------
__global__ __launch_bounds__(256) void k_fft_rho(float2* __restrict__ T,
                                                 const float2* __restrict__ zetaT,
                                                 const float2* __restrict__ tw1024f) {
  __shared__ float2 s[1024];     // 8 KB
  __shared__ float2 twl[1024];   // 8 KB
  const int j   = blockIdx.x;    // theta bin 0..255
  const int lb  = blockIdx.y;
  const int tid = threadIdx.x;
  {
    const float4* tp = (const float4*)tw1024f;
    float4* lp = (float4*)twl;
    for (int e = tid; e < 512; e += 256) lp[e] = tp[e];
  }
  float2* row = T + ((size_t)lb * ZROWS + j) * NRHO;
  {
    const float4* rp = (const float4*)row;
    for (int e = tid; e < 512; e += 256) {
      float4 v = rp[e];
      s[2 * e]     = make_float2(v.x, v.y);
      s[2 * e + 1] = make_float2(v.z, v.w);
    }
  }
  __syncthreads();
  // forward radix-4 DIF: natural -> base4-digit-reversed
  #pragma unroll
  for (int lq = 8; lq >= 0; lq -= 2) {
    const int q = 1 << lq, tfac = 256 >> lq;
    int jj = tid & (q - 1);
    int base = ((tid >> lq) << (lq + 2)) | jj;
    float2 a = s[base], b = s[base + q], c = s[base + 2 * q], d = s[base + 3 * q];
    float2 A = make_float2(a.x + c.x, a.y + c.y);
    float2 C = make_float2(a.x - c.x, a.y - c.y);
    float2 B = make_float2(b.x + d.x, b.y + d.y);
    float2 D = make_float2(b.x - d.x, b.y - d.y);
    float2 u0 = make_float2(A.x + B.x, A.y + B.y);
    float2 u2 = make_float2(A.x - B.x, A.y - B.y);
    float2 u1 = make_float2(C.x + D.y, C.y - D.x);   // C - iD
    float2 u3 = make_float2(C.x - D.y, C.y + D.x);   // C + iD
    int t1i = jj * tfac;
    s[base]         = u0;
    s[base + q]     = cmulf(u1, twl[t1i]);
    s[base + 2 * q] = cmulf(u2, twl[2 * t1i]);
    s[base + 3 * q] = cmulf(u3, twl[3 * t1i]);
    __syncthreads();
  }
  // pointwise * zeta (digit-reversed layout, normalizations folded in)
  {
    const float2* zrow = zetaT + (size_t)j * NRHO;
    for (int e = tid; e < 1024; e += 256)
      s[e] = cmulf(s[e], zrow[e]);
  }
  __syncthreads();
  // inverse radix-4 DIT: digit-reversed -> natural (scale folded into zeta)
  #pragma unroll
  for (int lq = 0; lq <= 8; lq += 2) {
    const int q = 1 << lq, tfac = 256 >> lq;
    int jj = tid & (q - 1);
    int base = ((tid >> lq) << (lq + 2)) | jj;
    int t1i = jj * tfac;
    float2 u0 = s[base];
    float2 u1 = cmulcf(s[base + q],     twl[t1i]);
    float2 u2 = cmulcf(s[base + 2 * q], twl[2 * t1i]);
    float2 u3 = cmulcf(s[base + 3 * q], twl[3 * t1i]);
    float2 t0 = make_float2(u0.x + u2.x, u0.y + u2.y);
    float2 t1 = make_float2(u0.x - u2.x, u0.y - u2.y);
    float2 t2 = make_float2(u1.x + u3.x, u1.y + u3.y);
    float2 t3 = make_float2(u1.x - u3.x, u1.y - u3.y);
    s[base]         = make_float2(t0.x + t2.x, t0.y + t2.y);
    s[base + 2 * q] = make_float2(t0.x - t2.x, t0.y - t2.y);
    s[base + q]     = make_float2(t1.x - t3.y, t1.y + t3.x);   // t1 + i t3
    s[base + 3 * q] = make_float2(t1.x + t3.y, t1.y - t3.x);   // t1 - i t3
    __syncthreads();
  }
  {
    float4* rp = (float4*)row;
    for (int e = tid; e < 512; e += 256) {
      float2 a = s[2 * e], b = s[2 * e + 1];
      rp[e] = make_float4(a.x, a.y, b.x, b.y);
    }
  }
}

// ---------------- Hermitian irfft(512) along theta, 8 rho-rows/block -> gkT[theta][rho] ----------------
__global__ __launch_bounds__(256) void k_irfft_th(const float2* __restrict__ T,
                                                  const float2* __restrict__ tw1024f,
                                                  float* __restrict__ gkT) {
  __shared__ float2 s[8][S8];
  __shared__ float2 twl[256];
  const int i0  = blockIdx.x * 8;
  const int lb  = blockIdx.y;
  const int tid = threadIdx.x;
  if (tid < 256) twl[tid] = tw1024f[2 * tid];
  __syncthreads();
  const float2* Tb = T + (size_t)lb * (ZROWS * NRHO);
  for (int e = tid; e < 2048; e += 256) {              // j<256 coalesced 64B reads
    int j = e >> 3, r = e & 7;
    float2 v = Tb[(size_t)j * NRHO + i0 + r];
    if (j == 0) v.y = 0.f;
    s[r][j] = v;
  }
  __syncthreads();
  for (int e = tid; e < 2048; e += 256) {              // Hermitian: j 256..511
    int j = 256 + (e >> 3), r = e & 7;
    s[r][j] = (j == 256) ? make_float2(0.f, 0.f)
                         : make_float2(s[r][512 - j].x, -s[r][512 - j].y);
  }
  for (int lh = 8; lh >= 0; --lh) {                    // DIF, sign +
    __syncthreads();
    for (int e = tid; e < 2048; e += 256) {
      int r = e >> 8, b = e & 255;
      int pos = b & ((1 << lh) - 1);
      int ia  = ((b >> lh) << (lh + 1)) | pos;
      float2 w = twl[pos << (8 - lh)]; w.y = -w.y;
      float2* sr = s[r];
      float2 u = sr[ia];
      float2 v = sr[ia + (1 << lh)];
      sr[ia] = make_float2(u.x + v.x, u.y + v.y);
      float2 d = make_float2(u.x - v.x, u.y - v.y);
      sr[ia + (1 << lh)] = cmulf(d, w);
    }
  }
  __syncthreads();
  float* gb = gkT + (size_t)lb * (NTH * NRHO);
  for (int e = tid; e < 4096; e += 256) {              // j<512, r<8: 32B segments
    int j = e >> 3, r = e & 7;
    gb[(size_t)j * NRHO + i0 + r] = s[r][__brev((unsigned)j) >> 23].x;
  }
}

// ---------------- resample to (angle, det); spans partition angles -> pure store ----------------
__global__ __launch_bounds__(256) void k_scatter(const float* __restrict__ gkT,
                                                 float* __restrict__ out,
                                                 int span, int b0, int chunk,
                                                 double d_rho, double aR) {
  int p = blockIdx.x * 256 + threadIdx.x;
  if (p >= PTOT) return;
  const int t = p >> 9;
  const int d = p & 511;
  const double beta = M_PI / 3.0;
  double th0 = (double)t * M_PI / 1024.0 - beta / 2.0;
  bool insp = (th0 >= (double)span * beta - beta / 2.0) &&
              (th0 <  (double)span * beta + beta / 2.0);
  if (!insp) return;
  double th00 = th0 - (double)span * beta;
  double d_th = 2.0 * beta / 512.0;
  double th_lp0 = -256.0 * d_th, th_lpL = 255.0 * d_th;
  double p1 = (th00 - th_lp0) / (th_lpL - th_lp0) * 511.0;
  double s0v = (d == 511) ? 1.0 : (double)d * (2.0 / 511.0) - 1.0;
  double p2 = log(s0v * aR + (1.0 - aR) * cos(th00));
  double rho0 = -1024.0 * d_rho, rhoL = -1.0 * d_rho;
  p2 = (p2 - rho0) / (rhoL - rho0) * 1023.0;
  double fy = floor(p2); fy = fy < 0.0 ? 0.0 : (fy > 1022.0 ? 1022.0 : fy);
  double fx = floor(p1); fx = fx < 0.0 ? 0.0 : (fx > 510.0 ? 510.0 : fx);
  int idx = (int)fx * 1024 + (int)fy;                  // gkT[theta][rho]
  for (int lb = 0; lb < chunk; ++lb)
    out[(size_t)(b0 + lb) * PTOT + p] = gkT[(size_t)lb * (NTH * NRHO) + idx];
}

// ---------------- launch ----------------
extern "C" void kernel_launch(void* const* d_in, const int* in_sizes, int n_in,
                              void* d_out, int out_size, void* d_ws, size_t ws_size,
                              hipStream_t stream) {
  (void)n_in; (void)out_size;
  const float* x = (const float*)d_in[0];
  float* out = (float*)d_out;
  const int batch = in_sizes[0] / (NIMG * NIMG);

  const size_t zeta_b = (size_t)ZROWS * NRHO * sizeof(float2);  // 2 MB
  const size_t idx_b  = (size_t)NRHO * NTH * sizeof(int);       // 2 MB
  const size_t tab_b  = 2048 * sizeof(double) * 2 + 1024 * sizeof(float2) * 2;
  const size_t per_b  = (size_t)ZROWS * NRHO * sizeof(float2)   // T
                      + (size_t)NTH * NRHO * sizeof(float);     // gkT
  int chunk = batch;
  while (chunk > 1 && zeta_b + idx_b + tab_b + (size_t)chunk * per_b > ws_size) chunk >>= 1;

  char* ws = (char*)d_ws;
  float2* zetaT   = (float2*)ws;  ws += zeta_b;
  int*    idx1    = (int*)ws;     ws += idx_b;
  double* Ltab    = (double*)ws;  ws += 2048 * sizeof(double);
  double* amp     = (double*)ws;  ws += 2048 * sizeof(double);
  float2* tw1024f = (float2*)ws;  ws += 1024 * sizeof(float2);
  float2* tw2048f = (float2*)ws;  ws += 1024 * sizeof(float2);
  float2* T       = (float2*)ws;  ws += (size_t)chunk * ZROWS * NRHO * sizeof(float2);
  float*  gkT     = (float*)ws;

  k_pre <<<dim3(8),    dim3(256), 0, stream>>>(Ltab, amp, tw1024f, tw2048f);
  k_zeta<<<dim3(1024), dim3(256), 0, stream>>>(Ltab, amp, tw2048f, zetaT,
                                               g_C.G_LA, g_C.dth, g_C.constv);

  for (int k = 0; k < 3; ++k) {
    k_idx_lp2c<<<dim3((NRHO * NTH) / 256), dim3(256), 0, stream>>>(idx1, k, g_C.d_rho, g_C.aR);
    for (int b0 = 0; b0 < batch; b0 += chunk) {
      int c = (b0 + chunk <= batch) ? chunk : (batch - b0);
      k_gather_rfft<<<dim3(NRHO / 8, c), dim3(256), 0, stream>>>(x, idx1, tw1024f, T, b0, g_C.d_rho);
      k_fft_rho    <<<dim3(ZROWS,   c), dim3(256), 0, stream>>>(T, zetaT, tw1024f);
      k_irfft_th   <<<dim3(NRHO / 8, c), dim3(256), 0, stream>>>(T, tw1024f, gkT);
      k_scatter    <<<dim3(PTOT / 256), dim3(256), 0, stream>>>(gkT, out, k, b0, c,
                                                                g_C.d_rho, g_C.aR);
    }
  }
}

// Round 5
// 393.104 us; speedup vs baseline: 2.3194x; 1.2990x over previous
//
#include <hip/hip_runtime.h>
#include <cmath>

#ifndef M_PI
#define M_PI 3.14159265358979323846
#endif

#define NIMG 512
#define NRHO 1024
#define NTH  512
#define ZROWS 256           // theta bins kept (bin 256 zeroed by zeta -> dropped)
#define S4   520            // LDS row stride (float2) for 4-row pair kernels
#define PTOT (1024*512)     // n_angles * n_det

// ---------------- host-side scalar constants ----------------
struct Consts { double G_LA, d_rho, aR, dth, constv; };

static Consts compute_consts() {
  Consts c;
  const double beta = M_PI / 3.0;
  const double sb = sin(beta / 2.0), cb = cos(beta / 2.0);
  const double aR = sb / (1.0 + sb);
  const double am = (cb - sb) / (1.0 + sb);
  double g = -1e300;
  const double start = -M_PI / 2.0, stop = M_PI / 2.0;
  const double delta = (stop - start) / 999.0;
  for (int i = 0; i < 1000; ++i) {
    double t = (i == 999) ? stop : (double)i * delta + start;
    double wre = aR * cos(t) + (1.0 - aR);
    double wim = aR * sin(t);
    double v = log(hypot(wre, wim)) + log(cos(beta / 2.0 - atan2(wim, wre)));
    if (!std::isnan(v) && v > g) g = v;
  }
  c.aR    = aR;
  c.G_LA  = g - log(am);
  c.d_rho = c.G_LA / 1024.0;
  double t1 = (-1023.0 / 2048.0) * beta * 2.0;
  double t0 = (-1024.0 / 2048.0) * beta * 2.0;
  c.dth = t1 - t0;
  c.constv = sqrt(0.5) * M_PI / 4.0 / aR / sqrt(2.0);
  return c;
}
static const Consts g_C = compute_consts();

// ---------------- device helpers ----------------
__device__ __forceinline__ float2 cmulf(float2 a, float2 b) {
  return make_float2(a.x * b.x - a.y * b.y, a.x * b.y + a.y * b.x);
}
__device__ __forceinline__ float2 cmulcf(float2 a, float2 w) {   // a * conj(w)
  return make_float2(a.x * w.x + a.y * w.y, a.y * w.x - a.x * w.y);
}
__device__ __forceinline__ int SW(int i) { return i ^ ((i >> 5) & 31); }  // LDS bank swizzle
__device__ __forceinline__ int dr4_10(int v) {                    // reverse 5 base-4 digits
  int r = 0;
  #pragma unroll
  for (int k = 0; k < 5; ++k) { r = (r << 2) | (v & 3); v >>= 2; }
  return r;
}
__device__ __forceinline__ double h_val(int jj) {
  const double ctab[11] = {-216254335.0, 679543284.0, -1412947389.0, 2415881496.0,
                           -3103579086.0, 2939942400.0, -2023224114.0, 984515304.0,
                           -321455811.0, 63253516.0, -5675265.0};
  int j = -1;
  if (jj <= 10) j = jj;
  else if (jj >= 2038) j = 2048 - jj;
  if (j < 0) return 1.0;
  double c = 1.0 + ctab[j] / 958003200.0;
  if (j == 0) c = 2.0 * (c - 0.5);
  return c;
}

// ---------------- precompute: L/amp tables + fp32 twiddle tables ----------------
__global__ __launch_bounds__(256) void k_pre(double* __restrict__ Ltab,
                                             double* __restrict__ amp,
                                             float2* __restrict__ tw1024f,
                                             float2* __restrict__ tw2048f) {
  int id = blockIdx.x * 256 + threadIdx.x;
  const double beta = M_PI / 3.0;
  if (id < 2048) {
    double th = ((double)(id - 1024) / 2048.0) * beta * 2.0;
    double L = log(cos(th));
    Ltab[id] = L;
    amp[id]  = h_val(id) * exp(-L);
  }
  if (id < 1024) {
    double a1 = -2.0 * M_PI * (double)id / 1024.0;
    double a2 = -2.0 * M_PI * (double)id / 2048.0;
    double s1, c1, s2, c2;
    sincos(a1, &s1, &c1); sincos(a2, &s2, &c2);
    tw1024f[id] = make_float2((float)c1, (float)s1);
    tw2048f[id] = make_float2((float)c2, (float)s2);
  }
}

// ---------------- zeta: fp32 2048-pt FFT per rho-frequency row ----------------
// zetaT[j][p], j<256 theta bin, p = base-4-digit-reversed rho freq.
// Includes const*dth/b3 and both inverse-FFT normalizations.
__global__ __launch_bounds__(256) void k_zeta(const double* __restrict__ Ltab,
                                              const double* __restrict__ amp,
                                              const float2* __restrict__ tw2048f,
                                              float2* __restrict__ zetaT,
                                              double G_LA, double dth, double constv) {
  __shared__ float2 s[2048];
  __shared__ float2 twl[1024];
  const int i   = blockIdx.x;    // k_rho row 0..1023
  const int tid = threadIdx.x;
  {
    const float4* tp = (const float4*)tw2048f;
    float4* lp = (float4*)twl;
    for (int e = tid; e < 512; e += 256) lp[e] = tp[e];
  }
  const double om = 2.0 * M_PI * (double)(i - 512) / G_LA;
  const double INV2PI = 1.0 / (2.0 * M_PI);
  for (int j = tid; j < 2048; j += 256) {
    int jj = (j + 1024) & 2047;
    double ph = -om * Ltab[jj] * INV2PI;
    ph -= floor(ph);
    float ang = (float)ph * 6.28318530717958647f;
    float sv, cv; __sincosf(ang, &sv, &cv);
    float a = (float)amp[jj];
    s[__brev((unsigned)j) >> 21] = make_float2(a * cv, a * sv);
  }
  for (int lh = 0; lh < 11; ++lh) {
    __syncthreads();
    for (int e = tid; e < 1024; e += 256) {
      int pos = e & ((1 << lh) - 1);
      int ia  = ((e >> lh) << (lh + 1)) | pos;
      float2 w = twl[pos << (10 - lh)];
      float2 u = s[ia];
      float2 v = cmulf(s[ia + (1 << lh)], w);
      s[ia]             = make_float2(u.x + v.x, u.y + v.y);
      s[ia + (1 << lh)] = make_float2(u.x - v.x, u.y - v.y);
    }
  }
  __syncthreads();
  const int i2 = (i + 512) & 1023;
  const int p  = dr4_10(i2);
  const double b3r = (4.0 + 2.0 * cos(2.0 * M_PI * (double)i2 / 1024.0)) / 6.0;
  if (tid < 256) {
    int j2 = tid;
    float2 z = make_float2(0.f, 0.f);
    if (i != 0) {
      float2 F = s[j2];
      double b3t = (4.0 + 2.0 * cos(2.0 * M_PI * (double)j2 / 512.0)) / 6.0;
      double sc = dth * constv / (b3r * b3t) * (1.0 / (1024.0 * 512.0));
      z = make_float2((float)((double)F.x * sc), (float)((double)F.y * sc));
    }
    zetaT[(size_t)j2 * 1024 + p] = z;
  }
}

// ---------------- gather index map, theta stored BIT-REVERSED ----------------
__global__ __launch_bounds__(256) void k_idx_lp2c(int* __restrict__ idx1, int span,
                                                  double d_rho, double aR) {
  int q = blockIdx.x * 256 + threadIdx.x;
  if (q >= NRHO * NTH) return;
  int i = q >> 9, jslot = q & 511;
  int j = __brev((unsigned)jslot) >> 23;             // theta position for this slot
  const double beta = M_PI / 3.0;
  double d_th = 2.0 * beta / 512.0;
  double th = (double)(j - 256) * d_th;
  double er = exp((double)(i - 1024) * d_rho);
  double t1 = er * cos(th), t2 = er * sin(th);
  double a = (double)span * beta + beta / 2.0;
  double ca = cos(a), sa = sin(a);
  double l1 = ((t1 - (1.0 - aR)) * ca - t2 * sa) / aR;
  double l2 = -(((t1 - (1.0 - aR)) * sa + t2 * ca) / aR);
  l1 = (l1 + 1.0) / 2.0 * 511.0;
  l2 = (l2 + 1.0) / 2.0 * 511.0;
  double fy = floor(l1); fy = fy < 0.0 ? 0.0 : (fy > 510.0 ? 510.0 : fy);
  double fx = floor(l2); fx = fx < 0.0 ? 0.0 : (fx > 510.0 ? 510.0 : fx);
  idx1[q] = (int)fy * 512 + (int)fx;
}

// ---------------- gather + paired rfft(512): 8 rho-rows = 4 complex FFTs ----------------
__global__ __launch_bounds__(256) void k_gather_rfft(const float* __restrict__ x,
                                                     const int* __restrict__ idx1,
                                                     const float2* __restrict__ tw1024f,
                                                     float2* __restrict__ T,
                                                     int b0, double d_rho) {
  __shared__ float2 s[4][S4];     // 16.6 KB
  __shared__ float2 twl[256];
  __shared__ float ers[8];
  const int i0  = blockIdx.x * 8;
  const int lb  = blockIdx.y;
  const int tid = threadIdx.x;
  twl[tid] = tw1024f[2 * tid];                       // exp(-2pi i m/512), m<256
  if (tid < 8) ers[tid] = (float)exp((double)(i0 + tid - 1024) * d_rho);
  __syncthreads();
  const float* xb = x + (size_t)(b0 + lb) * (NIMG * NIMG);
  // gather: idx pre-bit-reversed -> natural DIT slot order; int4 for ILP
  const int4* idx4 = (const int4*)idx1 + i0 * 128;
  for (int it = 0; it < 4; ++it) {
    int e4 = tid + (it << 8);                        // 0..1023
    int4 iv = idx4[e4];
    int r = e4 >> 7;                                 // rho row 0..7
    int jb = (e4 & 127) * 4;
    float er = ers[r];
    float* sm = (float*)s[r >> 1];
    int p = r & 1;
    sm[2 * SW(jb + 0) + p] = xb[iv.x] * er;
    sm[2 * SW(jb + 1) + p] = xb[iv.y] * er;
    sm[2 * SW(jb + 2) + p] = xb[iv.z] * er;
    sm[2 * SW(jb + 3) + p] = xb[iv.w] * er;
  }
  // 4 complex FFT-512, radix-2 DIT (input bit-reversed, output natural)
  for (int lh = 0; lh < 9; ++lh) {
    __syncthreads();
    for (int it = 0; it < 4; ++it) {
      int e = tid + (it << 8);
      int m = e >> 8, b = e & 255;
      int pos = b & ((1 << lh) - 1);
      int ia  = ((b >> lh) << (lh + 1)) | pos;
      float2 w = twl[pos << (8 - lh)];
      float2* sm = s[m];
      float2 u = sm[SW(ia)];
      float2 v = cmulf(sm[SW(ia + (1 << lh))], w);
      sm[SW(ia)]             = make_float2(u.x + v.x, u.y + v.y);
      sm[SW(ia + (1 << lh))] = make_float2(u.x - v.x, u.y - v.y);
    }
  }
  __syncthreads();
  // unpack pair spectra + transposed coalesced write (64B per theta bin)
  float2* Tb = T + (size_t)lb * (ZROWS * NRHO);
  for (int it = 0; it < 8; ++it) {
    int e = tid + (it << 8);                         // 0..2047
    int k = e >> 3, rr = e & 7;
    int m = rr >> 1, p = rr & 1;
    float2 Z  = s[m][SW(k)];
    float2 Zc = s[m][SW((512 - k) & 511)];
    float2 F;
    if (!p) F = make_float2(0.5f * (Z.x + Zc.x), 0.5f * (Z.y - Zc.y));
    else    F = make_float2(0.5f * (Z.y + Zc.y), 0.5f * (Zc.x - Z.x));
    Tb[(size_t)k * NRHO + i0 + rr] = F;
  }
}

// ---------------- rho: fft1024 * zeta * ifft1024, radix-4, one theta-bin/block ----------------
__global__ __launch_bounds__(256) void k_fft_rho(float2* __restrict__ T,
                                                 const float2* __restrict__ zetaT,
                                                 const float2* __restrict__ tw1024f) {
  __shared__ float2 s[1024];
  __shared__ float2 twl[1024];
  const int j   = blockIdx.x;
  const int lb  = blockIdx.y;
  const int tid = threadIdx.x;
  {
    const float4* tp = (const float4*)tw1024f;
    float4* lp = (float4*)twl;
    for (int e = tid; e < 512; e += 256) lp[e] = tp[e];
  }
  float2* row = T + ((size_t)lb * ZROWS + j) * NRHO;
  {
    const float4* rp = (const float4*)row;
    for (int e = tid; e < 512; e += 256) {
      float4 v = rp[e];
      s[2 * e]     = make_float2(v.x, v.y);
      s[2 * e + 1] = make_float2(v.z, v.w);
    }
  }
  __syncthreads();
  #pragma unroll
  for (int lq = 8; lq >= 0; lq -= 2) {
    const int q = 1 << lq, tfac = 256 >> lq;
    int jj = tid & (q - 1);
    int base = ((tid >> lq) << (lq + 2)) | jj;
    float2 a = s[base], b = s[base + q], c = s[base + 2 * q], d = s[base + 3 * q];
    float2 A = make_float2(a.x + c.x, a.y + c.y);
    float2 C = make_float2(a.x - c.x, a.y - c.y);
    float2 B = make_float2(b.x + d.x, b.y + d.y);
    float2 D = make_float2(b.x - d.x, b.y - d.y);
    float2 u0 = make_float2(A.x + B.x, A.y + B.y);
    float2 u2 = make_float2(A.x - B.x, A.y - B.y);
    float2 u1 = make_float2(C.x + D.y, C.y - D.x);
    float2 u3 = make_float2(C.x - D.y, C.y + D.x);
    int t1i = jj * tfac;
    s[base]         = u0;
    s[base + q]     = cmulf(u1, twl[t1i]);
    s[base + 2 * q] = cmulf(u2, twl[2 * t1i]);
    s[base + 3 * q] = cmulf(u3, twl[3 * t1i]);
    __syncthreads();
  }
  {
    const float2* zrow = zetaT + (size_t)j * NRHO;
    for (int e = tid; e < 1024; e += 256)
      s[e] = cmulf(s[e], zrow[e]);
  }
  __syncthreads();
  #pragma unroll
  for (int lq = 0; lq <= 8; lq += 2) {
    const int q = 1 << lq, tfac = 256 >> lq;
    int jj = tid & (q - 1);
    int base = ((tid >> lq) << (lq + 2)) | jj;
    int t1i = jj * tfac;
    float2 u0 = s[base];
    float2 u1 = cmulcf(s[base + q],     twl[t1i]);
    float2 u2 = cmulcf(s[base + 2 * q], twl[2 * t1i]);
    float2 u3 = cmulcf(s[base + 3 * q], twl[3 * t1i]);
    float2 t0 = make_float2(u0.x + u2.x, u0.y + u2.y);
    float2 t1 = make_float2(u0.x - u2.x, u0.y - u2.y);
    float2 t2 = make_float2(u1.x + u3.x, u1.y + u3.y);
    float2 t3 = make_float2(u1.x - u3.x, u1.y - u3.y);
    s[base]         = make_float2(t0.x + t2.x, t0.y + t2.y);
    s[base + 2 * q] = make_float2(t0.x - t2.x, t0.y - t2.y);
    s[base + q]     = make_float2(t1.x - t3.y, t1.y + t3.x);
    s[base + 3 * q] = make_float2(t1.x + t3.y, t1.y - t3.x);
    __syncthreads();
  }
  {
    float4* rp = (float4*)row;
    for (int e = tid; e < 512; e += 256) {
      float2 a = s[2 * e], b = s[2 * e + 1];
      rp[e] = make_float4(a.x, a.y, b.x, b.y);
    }
  }
}

// ---------------- paired Hermitian irfft(512): 8 rho-rows = 4 complex IFFTs ----------------
// Output gkT rows are in BIT-REVERSED theta order (scatter compensates).
__global__ __launch_bounds__(256) void k_irfft_th(const float2* __restrict__ T,
                                                  const float2* __restrict__ tw1024f,
                                                  float* __restrict__ gkT) {
  __shared__ float2 s[4][S4];
  __shared__ float2 twl[256];
  const int i0  = blockIdx.x * 8;
  const int lb  = blockIdx.y;
  const int tid = threadIdx.x;
  twl[tid] = tw1024f[2 * tid];
  const float2* Tb = T + (size_t)lb * (ZROWS * NRHO);
  __syncthreads();
  // stage A: raw F -> LDS (pair m holds F0 at SW(k), F1 at SW(256+k))
  for (int it = 0; it < 8; ++it) {
    int e = tid + (it << 8);
    int k = e >> 3, rr = e & 7;
    int m = rr >> 1, p = rr & 1;
    s[m][SW(k + 256 * p)] = Tb[(size_t)k * NRHO + i0 + rr];
  }
  __syncthreads();
  // stage B: build Z = F0 + i*F1 over k=0..511 (registers to avoid in-place hazard)
  float2 Zr[8];
  for (int it = 0; it < 8; ++it) {
    int e = tid + (it << 8);
    int m = e >> 9, k = e & 511;
    float2 z;
    if (k == 256) z = make_float2(0.f, 0.f);
    else {
      int k2 = (k < 256) ? k : 512 - k;
      float2 F0 = s[m][SW(k2)];
      float2 F1 = s[m][SW(256 + k2)];
      if (k2 == 0) { F0.y = 0.f; F1.y = 0.f; }       // numpy irfft ignores DC imag
      if (k < 256) z = make_float2(F0.x - F1.y, F0.y + F1.x);
      else         z = make_float2(F0.x + F1.y, F1.x - F0.y);
    }
    Zr[it] = z;
  }
  __syncthreads();
  for (int it = 0; it < 8; ++it) {
    int e = tid + (it << 8);
    int m = e >> 9, k = e & 511;
    s[m][SW(k)] = Zr[it];
  }
  // inverse DIF (sign +): natural in -> bit-reversed out
  for (int lh = 8; lh >= 0; --lh) {
    __syncthreads();
    for (int it = 0; it < 4; ++it) {
      int e = tid + (it << 8);
      int m = e >> 8, b = e & 255;
      int pos = b & ((1 << lh) - 1);
      int ia  = ((b >> lh) << (lh + 1)) | pos;
      float2 w = twl[pos << (8 - lh)];
      float2* sm = s[m];
      float2 u = sm[SW(ia)];
      float2 v = sm[SW(ia + (1 << lh))];
      sm[SW(ia)] = make_float2(u.x + v.x, u.y + v.y);
      float2 d = make_float2(u.x - v.x, u.y - v.y);
      sm[SW(ia + (1 << lh))] = cmulcf(d, w);
    }
  }
  __syncthreads();
  // write ALL 512 theta slots x 8 rho cols (4096 values) — R4 bug was it<8 here
  float* gb = gkT + (size_t)lb * (NTH * NRHO);
  for (int it = 0; it < 16; ++it) {
    int e = tid + (it << 8);                         // 0..4095
    int jslot = e >> 3, rr = e & 7;
    float2 z = s[rr >> 1][SW(jslot)];
    gb[(size_t)jslot * NRHO + i0 + rr] = (rr & 1) ? z.y : z.x;
  }
}

// ---------------- resample to (angle, det); gkT theta rows bit-reversed ----------------
__global__ __launch_bounds__(256) void k_scatter(const float* __restrict__ gkT,
                                                 float* __restrict__ out,
                                                 int span, int b0, int chunk,
                                                 double d_rho, double aR) {
  int p = blockIdx.x * 256 + threadIdx.x;
  if (p >= PTOT) return;
  const int t = p >> 9;
  const int d = p & 511;
  const double beta = M_PI / 3.0;
  double th0 = (double)t * M_PI / 1024.0 - beta / 2.0;
  bool insp = (th0 >= (double)span * beta - beta / 2.0) &&
              (th0 <  (double)span * beta + beta / 2.0);
  if (!insp) return;
  double th00 = th0 - (double)span * beta;
  double d_th = 2.0 * beta / 512.0;
  double th_lp0 = -256.0 * d_th, th_lpL = 255.0 * d_th;
  double p1 = (th00 - th_lp0) / (th_lpL - th_lp0) * 511.0;
  double s0v = (d == 511) ? 1.0 : (double)d * (2.0 / 511.0) - 1.0;
  double p2 = log(s0v * aR + (1.0 - aR) * cos(th00));
  double rho0 = -1024.0 * d_rho, rhoL = -1.0 * d_rho;
  p2 = (p2 - rho0) / (rhoL - rho0) * 1023.0;
  double fy = floor(p2); fy = fy < 0.0 ? 0.0 : (fy > 1022.0 ? 1022.0 : fy);
  double fx = floor(p1); fx = fx < 0.0 ? 0.0 : (fx > 510.0 ? 510.0 : fx);
  int row = __brev((unsigned)(int)fx) >> 23;         // bit-reversed theta row
  int idx = row * 1024 + (int)fy;
  for (int lb = 0; lb < chunk; ++lb)
    out[(size_t)(b0 + lb) * PTOT + p] = gkT[(size_t)lb * (NTH * NRHO) + idx];
}

// ---------------- launch ----------------
extern "C" void kernel_launch(void* const* d_in, const int* in_sizes, int n_in,
                              void* d_out, int out_size, void* d_ws, size_t ws_size,
                              hipStream_t stream) {
  (void)n_in; (void)out_size;
  const float* x = (const float*)d_in[0];
  float* out = (float*)d_out;
  const int batch = in_sizes[0] / (NIMG * NIMG);

  const size_t zeta_b = (size_t)ZROWS * NRHO * sizeof(float2);  // 2 MB
  const size_t idx_b  = (size_t)NRHO * NTH * sizeof(int);       // 2 MB
  const size_t tab_b  = 2048 * sizeof(double) * 2 + 1024 * sizeof(float2) * 2;
  const size_t per_b  = (size_t)ZROWS * NRHO * sizeof(float2)   // T
                      + (size_t)NTH * NRHO * sizeof(float);     // gkT
  int chunk = batch;
  while (chunk > 1 && zeta_b + idx_b + tab_b + (size_t)chunk * per_b > ws_size) chunk >>= 1;

  char* ws = (char*)d_ws;
  float2* zetaT   = (float2*)ws;  ws += zeta_b;
  int*    idx1    = (int*)ws;     ws += idx_b;
  double* Ltab    = (double*)ws;  ws += 2048 * sizeof(double);
  double* amp     = (double*)ws;  ws += 2048 * sizeof(double);
  float2* tw1024f = (float2*)ws;  ws += 1024 * sizeof(float2);
  float2* tw2048f = (float2*)ws;  ws += 1024 * sizeof(float2);
  float2* T       = (float2*)ws;  ws += (size_t)chunk * ZROWS * NRHO * sizeof(float2);
  float*  gkT     = (float*)ws;

  k_pre <<<dim3(8),    dim3(256), 0, stream>>>(Ltab, amp, tw1024f, tw2048f);
  k_zeta<<<dim3(1024), dim3(256), 0, stream>>>(Ltab, amp, tw2048f, zetaT,
                                               g_C.G_LA, g_C.dth, g_C.constv);

  for (int k = 0; k < 3; ++k) {
    k_idx_lp2c<<<dim3((NRHO * NTH) / 256), dim3(256), 0, stream>>>(idx1, k, g_C.d_rho, g_C.aR);
    for (int b0 = 0; b0 < batch; b0 += chunk) {
      int c = (b0 + chunk <= batch) ? chunk : (batch - b0);
      k_gather_rfft<<<dim3(NRHO / 8, c), dim3(256), 0, stream>>>(x, idx1, tw1024f, T, b0, g_C.d_rho);
      k_fft_rho    <<<dim3(ZROWS,   c), dim3(256), 0, stream>>>(T, zetaT, tw1024f);
      k_irfft_th   <<<dim3(NRHO / 8, c), dim3(256), 0, stream>>>(T, tw1024f, gkT);
      k_scatter    <<<dim3(PTOT / 256), dim3(256), 0, stream>>>(gkT, out, k, b0, c,
                                                                g_C.d_rho, g_C.aR);
    }
  }
}

// Round 6
// 363.152 us; speedup vs baseline: 2.5107x; 1.0825x over previous
//
#include <hip/hip_runtime.h>
#include <cmath>

#ifndef M_PI
#define M_PI 3.14159265358979323846
#endif

#define NIMG 512
#define NRHO 1024
#define NTH  512
#define ZROWS 256           // theta bins kept (bin 256 zeroed by zeta -> dropped)
#define S4   520            // LDS row stride (float2) for 4-row pair kernels
#define PTOT (1024*512)     // n_angles * n_det

// ---------------- host-side scalar constants ----------------
struct Consts { double G_LA, d_rho, aR, dth, constv; };

static Consts compute_consts() {
  Consts c;
  const double beta = M_PI / 3.0;
  const double sb = sin(beta / 2.0), cb = cos(beta / 2.0);
  const double aR = sb / (1.0 + sb);
  const double am = (cb - sb) / (1.0 + sb);
  double g = -1e300;
  const double start = -M_PI / 2.0, stop = M_PI / 2.0;
  const double delta = (stop - start) / 999.0;
  for (int i = 0; i < 1000; ++i) {
    double t = (i == 999) ? stop : (double)i * delta + start;
    double wre = aR * cos(t) + (1.0 - aR);
    double wim = aR * sin(t);
    double v = log(hypot(wre, wim)) + log(cos(beta / 2.0 - atan2(wim, wre)));
    if (!std::isnan(v) && v > g) g = v;
  }
  c.aR    = aR;
  c.G_LA  = g - log(am);
  c.d_rho = c.G_LA / 1024.0;
  double t1 = (-1023.0 / 2048.0) * beta * 2.0;
  double t0 = (-1024.0 / 2048.0) * beta * 2.0;
  c.dth = t1 - t0;
  c.constv = sqrt(0.5) * M_PI / 4.0 / aR / sqrt(2.0);
  return c;
}
static const Consts g_C = compute_consts();

// ---------------- device helpers ----------------
__device__ __forceinline__ float2 cmulf(float2 a, float2 b) {
  return make_float2(a.x * b.x - a.y * b.y, a.x * b.y + a.y * b.x);
}
__device__ __forceinline__ float2 cmulcf(float2 a, float2 w) {   // a * conj(w)
  return make_float2(a.x * w.x + a.y * w.y, a.y * w.x - a.x * w.y);
}
__device__ __forceinline__ int SW(int i) { return i ^ ((i >> 5) & 31); }  // LDS bank swizzle
__device__ __forceinline__ int dr4_10(int v) {                    // reverse 5 base-4 digits
  int r = 0;
  #pragma unroll
  for (int k = 0; k < 5; ++k) { r = (r << 2) | (v & 3); v >>= 2; }
  return r;
}
__device__ __forceinline__ double h_val(int jj) {
  const double ctab[11] = {-216254335.0, 679543284.0, -1412947389.0, 2415881496.0,
                           -3103579086.0, 2939942400.0, -2023224114.0, 984515304.0,
                           -321455811.0, 63253516.0, -5675265.0};
  int j = -1;
  if (jj <= 10) j = jj;
  else if (jj >= 2038) j = 2048 - jj;
  if (j < 0) return 1.0;
  double c = 1.0 + ctab[j] / 958003200.0;
  if (j == 0) c = 2.0 * (c - 0.5);
  return c;
}

// ---------------- precompute: L/amp tables + fp32 twiddle tables ----------------
__global__ __launch_bounds__(256) void k_pre(double* __restrict__ Ltab,
                                             double* __restrict__ amp,
                                             float2* __restrict__ tw1024f,
                                             float2* __restrict__ tw2048f) {
  int id = blockIdx.x * 256 + threadIdx.x;
  const double beta = M_PI / 3.0;
  if (id < 2048) {
    double th = ((double)(id - 1024) / 2048.0) * beta * 2.0;
    double L = log(cos(th));
    Ltab[id] = L;
    amp[id]  = h_val(id) * exp(-L);
  }
  if (id < 1024) {
    double a1 = -2.0 * M_PI * (double)id / 1024.0;
    double a2 = -2.0 * M_PI * (double)id / 2048.0;
    double s1, c1, s2, c2;
    sincos(a1, &s1, &c1); sincos(a2, &s2, &c2);
    tw1024f[id] = make_float2((float)c1, (float)s1);
    tw2048f[id] = make_float2((float)c2, (float)s2);
  }
}

// ---------------- zeta: fp32 2048-pt FFT per rho-frequency row ----------------
// zetaT[j][p], j<256 theta bin, p = base-4-digit-reversed rho freq.
// Includes const*dth/b3 and both inverse-FFT normalizations.
__global__ __launch_bounds__(256) void k_zeta(const double* __restrict__ Ltab,
                                              const double* __restrict__ amp,
                                              const float2* __restrict__ tw2048f,
                                              float2* __restrict__ zetaT,
                                              double G_LA, double dth, double constv) {
  __shared__ float2 s[2048];
  __shared__ float2 twl[1024];
  const int i   = blockIdx.x;    // k_rho row 0..1023
  const int tid = threadIdx.x;
  {
    const float4* tp = (const float4*)tw2048f;
    float4* lp = (float4*)twl;
    for (int e = tid; e < 512; e += 256) lp[e] = tp[e];
  }
  const double om = 2.0 * M_PI * (double)(i - 512) / G_LA;
  const double INV2PI = 1.0 / (2.0 * M_PI);
  for (int j = tid; j < 2048; j += 256) {
    int jj = (j + 1024) & 2047;
    double ph = -om * Ltab[jj] * INV2PI;
    ph -= floor(ph);
    float ang = (float)ph * 6.28318530717958647f;
    float sv, cv; __sincosf(ang, &sv, &cv);
    float a = (float)amp[jj];
    s[__brev((unsigned)j) >> 21] = make_float2(a * cv, a * sv);
  }
  for (int lh = 0; lh < 11; ++lh) {
    __syncthreads();
    for (int e = tid; e < 1024; e += 256) {
      int pos = e & ((1 << lh) - 1);
      int ia  = ((e >> lh) << (lh + 1)) | pos;
      float2 w = twl[pos << (10 - lh)];
      float2 u = s[ia];
      float2 v = cmulf(s[ia + (1 << lh)], w);
      s[ia]             = make_float2(u.x + v.x, u.y + v.y);
      s[ia + (1 << lh)] = make_float2(u.x - v.x, u.y - v.y);
    }
  }
  __syncthreads();
  const int i2 = (i + 512) & 1023;
  const int p  = dr4_10(i2);
  const double b3r = (4.0 + 2.0 * cos(2.0 * M_PI * (double)i2 / 1024.0)) / 6.0;
  if (tid < 256) {
    int j2 = tid;
    float2 z = make_float2(0.f, 0.f);
    if (i != 0) {
      float2 F = s[j2];
      double b3t = (4.0 + 2.0 * cos(2.0 * M_PI * (double)j2 / 512.0)) / 6.0;
      double sc = dth * constv / (b3r * b3t) * (1.0 / (1024.0 * 512.0));
      z = make_float2((float)((double)F.x * sc), (float)((double)F.y * sc));
    }
    zetaT[(size_t)j2 * 1024 + p] = z;
  }
}

// ---------------- gather index map, NATURAL theta order (coalesced) ----------------
__global__ __launch_bounds__(256) void k_idx_lp2c(int* __restrict__ idx1, int span,
                                                  double d_rho, double aR) {
  int q = blockIdx.x * 256 + threadIdx.x;
  if (q >= NRHO * NTH) return;
  int i = q >> 9, j = q & 511;
  const double beta = M_PI / 3.0;
  double d_th = 2.0 * beta / 512.0;
  double th = (double)(j - 256) * d_th;
  double er = exp((double)(i - 1024) * d_rho);
  double t1 = er * cos(th), t2 = er * sin(th);
  double a = (double)span * beta + beta / 2.0;
  double ca = cos(a), sa = sin(a);
  double l1 = ((t1 - (1.0 - aR)) * ca - t2 * sa) / aR;
  double l2 = -(((t1 - (1.0 - aR)) * sa + t2 * ca) / aR);
  l1 = (l1 + 1.0) / 2.0 * 511.0;
  l2 = (l2 + 1.0) / 2.0 * 511.0;
  double fy = floor(l1); fy = fy < 0.0 ? 0.0 : (fy > 510.0 ? 510.0 : fy);
  double fx = floor(l2); fx = fx < 0.0 ? 0.0 : (fx > 510.0 ? 510.0 : fx);
  idx1[q] = (int)fy * 512 + (int)fx;
}

// ---------------- gather + paired rfft(512): 8 rho-rows = 4 complex FFTs ----------------
// Thread tid: rho row r=tid>>5, 16 consecutive theta j=(tid&31)*16+u.
// 16 idx loaded to regs, 16 image gathers in flight, LDS slot = brev9(j).
__global__ __launch_bounds__(256) void k_gather_rfft(const float* __restrict__ x,
                                                     const int* __restrict__ idx1,
                                                     const float2* __restrict__ tw1024f,
                                                     float2* __restrict__ T,
                                                     int b0, double d_rho) {
  __shared__ float2 s[4][S4];     // 16.6 KB
  __shared__ float2 twl[256];
  const int bx  = blockIdx.x;
  const int g   = ((bx & 7) << 4) | (bx >> 3);       // XCD ring swizzle (128 blocks)
  const int i0  = g * 8;
  const int lb  = blockIdx.y;
  const int tid = threadIdx.x;
  twl[tid] = tw1024f[2 * tid];                       // exp(-2pi i m/512), m<256
  const int r  = tid >> 5;                           // rho row 0..7
  const int t5 = tid & 31;
  const float er = (float)exp((double)(i0 + r - 1024) * d_rho);
  const float* xb = x + (size_t)(b0 + lb) * (NIMG * NIMG);
  // 4 int4 = 16 consecutive-theta indices (coalesced 64B/thread)
  const int4* ip = (const int4*)(idx1 + (i0 + r) * 512 + t5 * 16);
  int4 i4[4];
  #pragma unroll
  for (int u = 0; u < 4; ++u) i4[u] = ip[u];
  float v[16];
  #pragma unroll
  for (int u = 0; u < 4; ++u) {                      // 16 gathers issued back-to-back
    v[4 * u + 0] = xb[i4[u].x];
    v[4 * u + 1] = xb[i4[u].y];
    v[4 * u + 2] = xb[i4[u].z];
    v[4 * u + 3] = xb[i4[u].w];
  }
  float* sm = (float*)s[r >> 1];
  const int p = r & 1;
  #pragma unroll
  for (int u = 0; u < 16; ++u) {
    int j = t5 * 16 + u;
    int slot = __brev((unsigned)j) >> 23;            // bit-reversal for free
    sm[2 * SW(slot) + p] = v[u] * er;
  }
  // 4 complex FFT-512, radix-2 DIT (input bit-reversed, output natural)
  for (int lh = 0; lh < 9; ++lh) {
    __syncthreads();
    for (int it = 0; it < 4; ++it) {
      int e = tid + (it << 8);
      int m = e >> 8, b = e & 255;
      int pos = b & ((1 << lh) - 1);
      int ia  = ((b >> lh) << (lh + 1)) | pos;
      float2 w = twl[pos << (8 - lh)];
      float2* smm = s[m];
      float2 u = smm[SW(ia)];
      float2 vv = cmulf(smm[SW(ia + (1 << lh))], w);
      smm[SW(ia)]             = make_float2(u.x + vv.x, u.y + vv.y);
      smm[SW(ia + (1 << lh))] = make_float2(u.x - vv.x, u.y - vv.y);
    }
  }
  __syncthreads();
  // unpack pair spectra + transposed coalesced write (64B per theta bin)
  float2* Tb = T + (size_t)lb * (ZROWS * NRHO);
  for (int it = 0; it < 8; ++it) {
    int e = tid + (it << 8);                         // 0..2047
    int k = e >> 3, rr = e & 7;
    int m = rr >> 1, pp = rr & 1;
    float2 Z  = s[m][SW(k)];
    float2 Zc = s[m][SW((512 - k) & 511)];
    float2 F;
    if (!pp) F = make_float2(0.5f * (Z.x + Zc.x), 0.5f * (Z.y - Zc.y));
    else     F = make_float2(0.5f * (Z.y + Zc.y), 0.5f * (Zc.x - Z.x));
    Tb[(size_t)k * NRHO + i0 + rr] = F;
  }
}

// ---------------- rho: fft1024 * zeta * ifft1024, radix-4, one theta-bin/block ----------------
__global__ __launch_bounds__(256) void k_fft_rho(float2* __restrict__ T,
                                                 const float2* __restrict__ zetaT,
                                                 const float2* __restrict__ tw1024f) {
  __shared__ float2 s[1024];
  __shared__ float2 twl[1024];
  const int j   = blockIdx.x;
  const int lb  = blockIdx.y;
  const int tid = threadIdx.x;
  {
    const float4* tp = (const float4*)tw1024f;
    float4* lp = (float4*)twl;
    for (int e = tid; e < 512; e += 256) lp[e] = tp[e];
  }
  float2* row = T + ((size_t)lb * ZROWS + j) * NRHO;
  {
    const float4* rp = (const float4*)row;
    for (int e = tid; e < 512; e += 256) {
      float4 v = rp[e];
      s[2 * e]     = make_float2(v.x, v.y);
      s[2 * e + 1] = make_float2(v.z, v.w);
    }
  }
  __syncthreads();
  #pragma unroll
  for (int lq = 8; lq >= 0; lq -= 2) {
    const int q = 1 << lq, tfac = 256 >> lq;
    int jj = tid & (q - 1);
    int base = ((tid >> lq) << (lq + 2)) | jj;
    float2 a = s[base], b = s[base + q], c = s[base + 2 * q], d = s[base + 3 * q];
    float2 A = make_float2(a.x + c.x, a.y + c.y);
    float2 C = make_float2(a.x - c.x, a.y - c.y);
    float2 B = make_float2(b.x + d.x, b.y + d.y);
    float2 D = make_float2(b.x - d.x, b.y - d.y);
    float2 u0 = make_float2(A.x + B.x, A.y + B.y);
    float2 u2 = make_float2(A.x - B.x, A.y - B.y);
    float2 u1 = make_float2(C.x + D.y, C.y - D.x);
    float2 u3 = make_float2(C.x - D.y, C.y + D.x);
    int t1i = jj * tfac;
    s[base]         = u0;
    s[base + q]     = cmulf(u1, twl[t1i]);
    s[base + 2 * q] = cmulf(u2, twl[2 * t1i]);
    s[base + 3 * q] = cmulf(u3, twl[3 * t1i]);
    __syncthreads();
  }
  {
    const float2* zrow = zetaT + (size_t)j * NRHO;
    for (int e = tid; e < 1024; e += 256)
      s[e] = cmulf(s[e], zrow[e]);
  }
  __syncthreads();
  #pragma unroll
  for (int lq = 0; lq <= 8; lq += 2) {
    const int q = 1 << lq, tfac = 256 >> lq;
    int jj = tid & (q - 1);
    int base = ((tid >> lq) << (lq + 2)) | jj;
    int t1i = jj * tfac;
    float2 u0 = s[base];
    float2 u1 = cmulcf(s[base + q],     twl[t1i]);
    float2 u2 = cmulcf(s[base + 2 * q], twl[2 * t1i]);
    float2 u3 = cmulcf(s[base + 3 * q], twl[3 * t1i]);
    float2 t0 = make_float2(u0.x + u2.x, u0.y + u2.y);
    float2 t1 = make_float2(u0.x - u2.x, u0.y - u2.y);
    float2 t2 = make_float2(u1.x + u3.x, u1.y + u3.y);
    float2 t3 = make_float2(u1.x - u3.x, u1.y - u3.y);
    s[base]         = make_float2(t0.x + t2.x, t0.y + t2.y);
    s[base + 2 * q] = make_float2(t0.x - t2.x, t0.y - t2.y);
    s[base + q]     = make_float2(t1.x - t3.y, t1.y + t3.x);
    s[base + 3 * q] = make_float2(t1.x + t3.y, t1.y - t3.x);
    __syncthreads();
  }
  {
    float4* rp = (float4*)row;
    for (int e = tid; e < 512; e += 256) {
      float2 a = s[2 * e], b = s[2 * e + 1];
      rp[e] = make_float4(a.x, a.y, b.x, b.y);
    }
  }
}

// ---------------- paired Hermitian irfft(512): 8 rho-rows = 4 complex IFFTs ----------------
// Output gkT rows are in BIT-REVERSED theta order (scatter compensates).
__global__ __launch_bounds__(256) void k_irfft_th(const float2* __restrict__ T,
                                                  const float2* __restrict__ tw1024f,
                                                  float* __restrict__ gkT) {
  __shared__ float2 s[4][S4];
  __shared__ float2 twl[256];
  const int i0  = blockIdx.x * 8;
  const int lb  = blockIdx.y;
  const int tid = threadIdx.x;
  twl[tid] = tw1024f[2 * tid];
  const float2* Tb = T + (size_t)lb * (ZROWS * NRHO);
  __syncthreads();
  // stage A: raw F -> LDS (pair m holds F0 at SW(k), F1 at SW(256+k))
  for (int it = 0; it < 8; ++it) {
    int e = tid + (it << 8);
    int k = e >> 3, rr = e & 7;
    int m = rr >> 1, p = rr & 1;
    s[m][SW(k + 256 * p)] = Tb[(size_t)k * NRHO + i0 + rr];
  }
  __syncthreads();
  // stage B: build Z = F0 + i*F1 over k=0..511 (registers to avoid in-place hazard)
  float2 Zr[8];
  for (int it = 0; it < 8; ++it) {
    int e = tid + (it << 8);
    int m = e >> 9, k = e & 511;
    float2 z;
    if (k == 256) z = make_float2(0.f, 0.f);
    else {
      int k2 = (k < 256) ? k : 512 - k;
      float2 F0 = s[m][SW(k2)];
      float2 F1 = s[m][SW(256 + k2)];
      if (k2 == 0) { F0.y = 0.f; F1.y = 0.f; }       // numpy irfft ignores DC imag
      if (k < 256) z = make_float2(F0.x - F1.y, F0.y + F1.x);
      else         z = make_float2(F0.x + F1.y, F1.x - F0.y);
    }
    Zr[it] = z;
  }
  __syncthreads();
  for (int it = 0; it < 8; ++it) {
    int e = tid + (it << 8);
    int m = e >> 9, k = e & 511;
    s[m][SW(k)] = Zr[it];
  }
  // inverse DIF (sign +): natural in -> bit-reversed out
  for (int lh = 8; lh >= 0; --lh) {
    __syncthreads();
    for (int it = 0; it < 4; ++it) {
      int e = tid + (it << 8);
      int m = e >> 8, b = e & 255;
      int pos = b & ((1 << lh) - 1);
      int ia  = ((b >> lh) << (lh + 1)) | pos;
      float2 w = twl[pos << (8 - lh)];
      float2* sm = s[m];
      float2 u = sm[SW(ia)];
      float2 v = sm[SW(ia + (1 << lh))];
      sm[SW(ia)] = make_float2(u.x + v.x, u.y + v.y);
      float2 d = make_float2(u.x - v.x, u.y - v.y);
      sm[SW(ia + (1 << lh))] = cmulcf(d, w);
    }
  }
  __syncthreads();
  // write ALL 512 theta slots x 8 rho cols (4096 values)
  float* gb = gkT + (size_t)lb * (NTH * NRHO);
  for (int it = 0; it < 16; ++it) {
    int e = tid + (it << 8);                         // 0..4095
    int jslot = e >> 3, rr = e & 7;
    float2 z = s[rr >> 1][SW(jslot)];
    gb[(size_t)jslot * NRHO + i0 + rr] = (rr & 1) ? z.y : z.x;
  }
}

// ---------------- resample to (angle, det); gkT theta rows bit-reversed ----------------
__global__ __launch_bounds__(256) void k_scatter(const float* __restrict__ gkT,
                                                 float* __restrict__ out,
                                                 int span, int b0, int chunk,
                                                 double d_rho, double aR) {
  int p = blockIdx.x * 256 + threadIdx.x;
  if (p >= PTOT) return;
  const int t = p >> 9;
  const int d = p & 511;
  const double beta = M_PI / 3.0;
  double th0 = (double)t * M_PI / 1024.0 - beta / 2.0;
  bool insp = (th0 >= (double)span * beta - beta / 2.0) &&
              (th0 <  (double)span * beta + beta / 2.0);
  if (!insp) return;
  double th00 = th0 - (double)span * beta;
  double d_th = 2.0 * beta / 512.0;
  double th_lp0 = -256.0 * d_th, th_lpL = 255.0 * d_th;
  double p1 = (th00 - th_lp0) / (th_lpL - th_lp0) * 511.0;
  double s0v = (d == 511) ? 1.0 : (double)d * (2.0 / 511.0) - 1.0;
  double p2 = log(s0v * aR + (1.0 - aR) * cos(th00));
  double rho0 = -1024.0 * d_rho, rhoL = -1.0 * d_rho;
  p2 = (p2 - rho0) / (rhoL - rho0) * 1023.0;
  double fy = floor(p2); fy = fy < 0.0 ? 0.0 : (fy > 1022.0 ? 1022.0 : fy);
  double fx = floor(p1); fx = fx < 0.0 ? 0.0 : (fx > 510.0 ? 510.0 : fx);
  int row = __brev((unsigned)(int)fx) >> 23;         // bit-reversed theta row
  int idx = row * 1024 + (int)fy;
  for (int lb = 0; lb < chunk; ++lb)
    out[(size_t)(b0 + lb) * PTOT + p] = gkT[(size_t)lb * (NTH * NRHO) + idx];
}

// ---------------- launch ----------------
extern "C" void kernel_launch(void* const* d_in, const int* in_sizes, int n_in,
                              void* d_out, int out_size, void* d_ws, size_t ws_size,
                              hipStream_t stream) {
  (void)n_in; (void)out_size;
  const float* x = (const float*)d_in[0];
  float* out = (float*)d_out;
  const int batch = in_sizes[0] / (NIMG * NIMG);

  const size_t zeta_b = (size_t)ZROWS * NRHO * sizeof(float2);  // 2 MB
  const size_t idx_b  = (size_t)NRHO * NTH * sizeof(int);       // 2 MB
  const size_t tab_b  = 2048 * sizeof(double) * 2 + 1024 * sizeof(float2) * 2;
  const size_t per_b  = (size_t)ZROWS * NRHO * sizeof(float2)   // T
                      + (size_t)NTH * NRHO * sizeof(float);     // gkT
  int chunk = batch;
  while (chunk > 1 && zeta_b + idx_b + tab_b + (size_t)chunk * per_b > ws_size) chunk >>= 1;

  char* ws = (char*)d_ws;
  float2* zetaT   = (float2*)ws;  ws += zeta_b;
  int*    idx1    = (int*)ws;     ws += idx_b;
  double* Ltab    = (double*)ws;  ws += 2048 * sizeof(double);
  double* amp     = (double*)ws;  ws += 2048 * sizeof(double);
  float2* tw1024f = (float2*)ws;  ws += 1024 * sizeof(float2);
  float2* tw2048f = (float2*)ws;  ws += 1024 * sizeof(float2);
  float2* T       = (float2*)ws;  ws += (size_t)chunk * ZROWS * NRHO * sizeof(float2);
  float*  gkT     = (float*)ws;

  k_pre <<<dim3(8),    dim3(256), 0, stream>>>(Ltab, amp, tw1024f, tw2048f);
  k_zeta<<<dim3(1024), dim3(256), 0, stream>>>(Ltab, amp, tw2048f, zetaT,
                                               g_C.G_LA, g_C.dth, g_C.constv);

  for (int k = 0; k < 3; ++k) {
    k_idx_lp2c<<<dim3((NRHO * NTH) / 256), dim3(256), 0, stream>>>(idx1, k, g_C.d_rho, g_C.aR);
    for (int b0 = 0; b0 < batch; b0 += chunk) {
      int c = (b0 + chunk <= batch) ? chunk : (batch - b0);
      k_gather_rfft<<<dim3(NRHO / 8, c), dim3(256), 0, stream>>>(x, idx1, tw1024f, T, b0, g_C.d_rho);
      k_fft_rho    <<<dim3(ZROWS,   c), dim3(256), 0, stream>>>(T, zetaT, tw1024f);
      k_irfft_th   <<<dim3(NRHO / 8, c), dim3(256), 0, stream>>>(T, tw1024f, gkT);
      k_scatter    <<<dim3(PTOT / 256), dim3(256), 0, stream>>>(gkT, out, k, b0, c,
                                                                g_C.d_rho, g_C.aR);
    }
  }
}

// Round 7
// 319.504 us; speedup vs baseline: 2.8537x; 1.1366x over previous
//
#include <hip/hip_runtime.h>
#include <cmath>

#ifndef M_PI
#define M_PI 3.14159265358979323846
#endif

#define NIMG 512
#define NRHO 1024
#define NTH  512
#define ZROWS 256           // theta bins kept (bin 256 zeroed by zeta -> dropped)
#define S4   520            // LDS row stride (float2) for 4-row pair kernels
#define PTOT (1024*512)     // n_angles * n_det
#define NSPAN 3

// ---------------- host-side scalar constants ----------------
struct Consts { double G_LA, d_rho, aR, dth, constv; };

static Consts compute_consts() {
  Consts c;
  const double beta = M_PI / 3.0;
  const double sb = sin(beta / 2.0), cb = cos(beta / 2.0);
  const double aR = sb / (1.0 + sb);
  const double am = (cb - sb) / (1.0 + sb);
  double g = -1e300;
  const double start = -M_PI / 2.0, stop = M_PI / 2.0;
  const double delta = (stop - start) / 999.0;
  for (int i = 0; i < 1000; ++i) {
    double t = (i == 999) ? stop : (double)i * delta + start;
    double wre = aR * cos(t) + (1.0 - aR);
    double wim = aR * sin(t);
    double v = log(hypot(wre, wim)) + log(cos(beta / 2.0 - atan2(wim, wre)));
    if (!std::isnan(v) && v > g) g = v;
  }
  c.aR    = aR;
  c.G_LA  = g - log(am);
  c.d_rho = c.G_LA / 1024.0;
  double t1 = (-1023.0 / 2048.0) * beta * 2.0;
  double t0 = (-1024.0 / 2048.0) * beta * 2.0;
  c.dth = t1 - t0;
  c.constv = sqrt(0.5) * M_PI / 4.0 / aR / sqrt(2.0);
  return c;
}
static const Consts g_C = compute_consts();

// ---------------- device helpers ----------------
__device__ __forceinline__ float2 cmulf(float2 a, float2 b) {
  return make_float2(a.x * b.x - a.y * b.y, a.x * b.y + a.y * b.x);
}
__device__ __forceinline__ float2 cmulcf(float2 a, float2 w) {   // a * conj(w)
  return make_float2(a.x * w.x + a.y * w.y, a.y * w.x - a.x * w.y);
}
__device__ __forceinline__ int SW(int i) { return i ^ ((i >> 5) & 31); }  // LDS bank swizzle
__device__ __forceinline__ int dr4_10(int v) {                    // reverse 5 base-4 digits
  int r = 0;
  #pragma unroll
  for (int k = 0; k < 5; ++k) { r = (r << 2) | (v & 3); v >>= 2; }
  return r;
}
__device__ __forceinline__ double h_val(int jj) {
  const double ctab[11] = {-216254335.0, 679543284.0, -1412947389.0, 2415881496.0,
                           -3103579086.0, 2939942400.0, -2023224114.0, 984515304.0,
                           -321455811.0, 63253516.0, -5675265.0};
  int j = -1;
  if (jj <= 10) j = jj;
  else if (jj >= 2038) j = 2048 - jj;
  if (j < 0) return 1.0;
  double c = 1.0 + ctab[j] / 958003200.0;
  if (j == 0) c = 2.0 * (c - 0.5);
  return c;
}

// ---------------- precompute: L/amp tables + fp32 twiddle tables ----------------
__global__ __launch_bounds__(256) void k_pre(double* __restrict__ Ltab,
                                             double* __restrict__ amp,
                                             float2* __restrict__ tw1024f,
                                             float2* __restrict__ tw2048f) {
  int id = blockIdx.x * 256 + threadIdx.x;
  const double beta = M_PI / 3.0;
  if (id < 2048) {
    double th = ((double)(id - 1024) / 2048.0) * beta * 2.0;
    double L = log(cos(th));
    Ltab[id] = L;
    amp[id]  = h_val(id) * exp(-L);
  }
  if (id < 1024) {
    double a1 = -2.0 * M_PI * (double)id / 1024.0;
    double a2 = -2.0 * M_PI * (double)id / 2048.0;
    double s1, c1, s2, c2;
    sincos(a1, &s1, &c1); sincos(a2, &s2, &c2);
    tw1024f[id] = make_float2((float)c1, (float)s1);
    tw2048f[id] = make_float2((float)c2, (float)s2);
  }
}

// ---------------- zeta: fp32 2048-pt FFT per rho-frequency row ----------------
// zetaT[j][p], j<256 theta bin, p = base-4-digit-reversed rho freq.
// Includes const*dth/b3 and both inverse-FFT normalizations.
__global__ __launch_bounds__(256) void k_zeta(const double* __restrict__ Ltab,
                                              const double* __restrict__ amp,
                                              const float2* __restrict__ tw2048f,
                                              float2* __restrict__ zetaT,
                                              double G_LA, double dth, double constv) {
  __shared__ float2 s[2048];
  __shared__ float2 twl[1024];
  const int i   = blockIdx.x;    // k_rho row 0..1023
  const int tid = threadIdx.x;
  {
    const float4* tp = (const float4*)tw2048f;
    float4* lp = (float4*)twl;
    for (int e = tid; e < 512; e += 256) lp[e] = tp[e];
  }
  const double om = 2.0 * M_PI * (double)(i - 512) / G_LA;
  const double INV2PI = 1.0 / (2.0 * M_PI);
  for (int j = tid; j < 2048; j += 256) {
    int jj = (j + 1024) & 2047;
    double ph = -om * Ltab[jj] * INV2PI;
    ph -= floor(ph);
    float ang = (float)ph * 6.28318530717958647f;
    float sv, cv; __sincosf(ang, &sv, &cv);
    float a = (float)amp[jj];
    s[__brev((unsigned)j) >> 21] = make_float2(a * cv, a * sv);
  }
  for (int lh = 0; lh < 11; ++lh) {
    __syncthreads();
    for (int e = tid; e < 1024; e += 256) {
      int pos = e & ((1 << lh) - 1);
      int ia  = ((e >> lh) << (lh + 1)) | pos;
      float2 w = twl[pos << (10 - lh)];
      float2 u = s[ia];
      float2 v = cmulf(s[ia + (1 << lh)], w);
      s[ia]             = make_float2(u.x + v.x, u.y + v.y);
      s[ia + (1 << lh)] = make_float2(u.x - v.x, u.y - v.y);
    }
  }
  __syncthreads();
  const int i2 = (i + 512) & 1023;
  const int p  = dr4_10(i2);
  const double b3r = (4.0 + 2.0 * cos(2.0 * M_PI * (double)i2 / 1024.0)) / 6.0;
  if (tid < 256) {
    int j2 = tid;
    float2 z = make_float2(0.f, 0.f);
    if (i != 0) {
      float2 F = s[j2];
      double b3t = (4.0 + 2.0 * cos(2.0 * M_PI * (double)j2 / 512.0)) / 6.0;
      double sc = dth * constv / (b3r * b3t) * (1.0 / (1024.0 * 512.0));
      z = make_float2((float)((double)F.x * sc), (float)((double)F.y * sc));
    }
    zetaT[(size_t)j2 * 1024 + p] = z;
  }
}

// ---------------- gather index map, ALL spans, natural theta order ----------------
__global__ __launch_bounds__(256) void k_idx_lp2c(int* __restrict__ idx1,
                                                  double d_rho, double aR) {
  int q = blockIdx.x * 256 + threadIdx.x;
  int span = q >> 19;                                // q / (NRHO*NTH)
  int ql = q & (NRHO * NTH - 1);
  int i = ql >> 9, j = ql & 511;
  const double beta = M_PI / 3.0;
  double d_th = 2.0 * beta / 512.0;
  double th = (double)(j - 256) * d_th;
  double er = exp((double)(i - 1024) * d_rho);
  double t1 = er * cos(th), t2 = er * sin(th);
  double a = (double)span * beta + beta / 2.0;
  double ca = cos(a), sa = sin(a);
  double l1 = ((t1 - (1.0 - aR)) * ca - t2 * sa) / aR;
  double l2 = -(((t1 - (1.0 - aR)) * sa + t2 * ca) / aR);
  l1 = (l1 + 1.0) / 2.0 * 511.0;
  l2 = (l2 + 1.0) / 2.0 * 511.0;
  double fy = floor(l1); fy = fy < 0.0 ? 0.0 : (fy > 510.0 ? 510.0 : fy);
  double fx = floor(l2); fx = fx < 0.0 ? 0.0 : (fx > 510.0 ? 510.0 : fx);
  idx1[q] = (int)fy * 512 + (int)fx;
}

// ---------------- gather + paired rfft(512): 8 rho-rows = 4 complex FFTs ----------------
// blockIdx.z = span. Thread tid: rho row r=tid>>5, 16 consecutive theta.
__global__ __launch_bounds__(256) void k_gather_rfft(const float* __restrict__ x,
                                                     const int* __restrict__ idx1,
                                                     const float2* __restrict__ tw1024f,
                                                     float2* __restrict__ T,
                                                     int b0, double d_rho) {
  __shared__ float2 s[4][S4];     // 16.6 KB
  __shared__ float2 twl[256];
  const int bx   = blockIdx.x;
  const int g    = ((bx & 7) << 4) | (bx >> 3);      // XCD ring swizzle (128 blocks)
  const int i0   = g * 8;
  const int lb   = blockIdx.y;
  const int span = blockIdx.z;
  const int tid  = threadIdx.x;
  twl[tid] = tw1024f[2 * tid];                       // exp(-2pi i m/512), m<256
  const int r  = tid >> 5;                           // rho row 0..7
  const int t5 = tid & 31;
  const float er = (float)exp((double)(i0 + r - 1024) * d_rho);
  const float* xb = x + (size_t)(b0 + lb) * (NIMG * NIMG);
  const int4* ip = (const int4*)(idx1 + span * (NRHO * NTH) + (i0 + r) * 512 + t5 * 16);
  int4 i4[4];
  #pragma unroll
  for (int u = 0; u < 4; ++u) i4[u] = ip[u];
  float v[16];
  #pragma unroll
  for (int u = 0; u < 4; ++u) {                      // 16 gathers issued back-to-back
    v[4 * u + 0] = xb[i4[u].x];
    v[4 * u + 1] = xb[i4[u].y];
    v[4 * u + 2] = xb[i4[u].z];
    v[4 * u + 3] = xb[i4[u].w];
  }
  float* sm = (float*)s[r >> 1];
  const int p = r & 1;
  #pragma unroll
  for (int u = 0; u < 16; ++u) {
    int j = t5 * 16 + u;
    int slot = __brev((unsigned)j) >> 23;            // bit-reversal for free
    sm[2 * SW(slot) + p] = v[u] * er;
  }
  // 4 complex FFT-512, radix-2 DIT (input bit-reversed, output natural)
  for (int lh = 0; lh < 9; ++lh) {
    __syncthreads();
    for (int it = 0; it < 4; ++it) {
      int e = tid + (it << 8);
      int m = e >> 8, b = e & 255;
      int pos = b & ((1 << lh) - 1);
      int ia  = ((b >> lh) << (lh + 1)) | pos;
      float2 w = twl[pos << (8 - lh)];
      float2* smm = s[m];
      float2 u = smm[SW(ia)];
      float2 vv = cmulf(smm[SW(ia + (1 << lh))], w);
      smm[SW(ia)]             = make_float2(u.x + vv.x, u.y + vv.y);
      smm[SW(ia + (1 << lh))] = make_float2(u.x - vv.x, u.y - vv.y);
    }
  }
  __syncthreads();
  // unpack pair spectra + transposed coalesced write (64B per theta bin)
  float2* Tb = T + (size_t)(span * gridDim.y + lb) * (ZROWS * NRHO);
  for (int it = 0; it < 8; ++it) {
    int e = tid + (it << 8);                         // 0..2047
    int k = e >> 3, rr = e & 7;
    int m = rr >> 1, pp = rr & 1;
    float2 Z  = s[m][SW(k)];
    float2 Zc = s[m][SW((512 - k) & 511)];
    float2 F;
    if (!pp) F = make_float2(0.5f * (Z.x + Zc.x), 0.5f * (Z.y - Zc.y));
    else     F = make_float2(0.5f * (Z.y + Zc.y), 0.5f * (Zc.x - Z.x));
    Tb[(size_t)k * NRHO + i0 + rr] = F;
  }
}

// ---------------- rho: fft1024 * zeta * ifft1024, radix-4, one theta-bin/block ----------------
__global__ __launch_bounds__(256) void k_fft_rho(float2* __restrict__ T,
                                                 const float2* __restrict__ zetaT,
                                                 const float2* __restrict__ tw1024f) {
  __shared__ float2 s[1024];
  __shared__ float2 twl[1024];
  const int j    = blockIdx.x;
  const int lb   = blockIdx.y;
  const int span = blockIdx.z;
  const int tid  = threadIdx.x;
  {
    const float4* tp = (const float4*)tw1024f;
    float4* lp = (float4*)twl;
    for (int e = tid; e < 512; e += 256) lp[e] = tp[e];
  }
  float2* row = T + ((size_t)(span * gridDim.y + lb) * ZROWS + j) * NRHO;
  {
    const float4* rp = (const float4*)row;
    for (int e = tid; e < 512; e += 256) {
      float4 v = rp[e];
      s[2 * e]     = make_float2(v.x, v.y);
      s[2 * e + 1] = make_float2(v.z, v.w);
    }
  }
  __syncthreads();
  #pragma unroll
  for (int lq = 8; lq >= 0; lq -= 2) {
    const int q = 1 << lq, tfac = 256 >> lq;
    int jj = tid & (q - 1);
    int base = ((tid >> lq) << (lq + 2)) | jj;
    float2 a = s[base], b = s[base + q], c = s[base + 2 * q], d = s[base + 3 * q];
    float2 A = make_float2(a.x + c.x, a.y + c.y);
    float2 C = make_float2(a.x - c.x, a.y - c.y);
    float2 B = make_float2(b.x + d.x, b.y + d.y);
    float2 D = make_float2(b.x - d.x, b.y - d.y);
    float2 u0 = make_float2(A.x + B.x, A.y + B.y);
    float2 u2 = make_float2(A.x - B.x, A.y - B.y);
    float2 u1 = make_float2(C.x + D.y, C.y - D.x);
    float2 u3 = make_float2(C.x - D.y, C.y + D.x);
    int t1i = jj * tfac;
    s[base]         = u0;
    s[base + q]     = cmulf(u1, twl[t1i]);
    s[base + 2 * q] = cmulf(u2, twl[2 * t1i]);
    s[base + 3 * q] = cmulf(u3, twl[3 * t1i]);
    __syncthreads();
  }
  {
    const float2* zrow = zetaT + (size_t)j * NRHO;
    for (int e = tid; e < 1024; e += 256)
      s[e] = cmulf(s[e], zrow[e]);
  }
  __syncthreads();
  #pragma unroll
  for (int lq = 0; lq <= 8; lq += 2) {
    const int q = 1 << lq, tfac = 256 >> lq;
    int jj = tid & (q - 1);
    int base = ((tid >> lq) << (lq + 2)) | jj;
    int t1i = jj * tfac;
    float2 u0 = s[base];
    float2 u1 = cmulcf(s[base + q],     twl[t1i]);
    float2 u2 = cmulcf(s[base + 2 * q], twl[2 * t1i]);
    float2 u3 = cmulcf(s[base + 3 * q], twl[3 * t1i]);
    float2 t0 = make_float2(u0.x + u2.x, u0.y + u2.y);
    float2 t1 = make_float2(u0.x - u2.x, u0.y - u2.y);
    float2 t2 = make_float2(u1.x + u3.x, u1.y + u3.y);
    float2 t3 = make_float2(u1.x - u3.x, u1.y - u3.y);
    s[base]         = make_float2(t0.x + t2.x, t0.y + t2.y);
    s[base + 2 * q] = make_float2(t0.x - t2.x, t0.y - t2.y);
    s[base + q]     = make_float2(t1.x - t3.y, t1.y + t3.x);
    s[base + 3 * q] = make_float2(t1.x + t3.y, t1.y - t3.x);
    __syncthreads();
  }
  {
    float4* rp = (float4*)row;
    for (int e = tid; e < 512; e += 256) {
      float2 a = s[2 * e], b = s[2 * e + 1];
      rp[e] = make_float4(a.x, a.y, b.x, b.y);
    }
  }
}

// ---------------- paired Hermitian irfft(512): 8 rho-rows = 4 complex IFFTs ----------------
// Output gkT rows are in BIT-REVERSED theta order (scatter compensates).
__global__ __launch_bounds__(256) void k_irfft_th(const float2* __restrict__ T,
                                                  const float2* __restrict__ tw1024f,
                                                  float* __restrict__ gkT) {
  __shared__ float2 s[4][S4];
  __shared__ float2 twl[256];
  const int i0   = blockIdx.x * 8;
  const int lb   = blockIdx.y;
  const int span = blockIdx.z;
  const int tid  = threadIdx.x;
  twl[tid] = tw1024f[2 * tid];
  const float2* Tb = T + (size_t)(span * gridDim.y + lb) * (ZROWS * NRHO);
  __syncthreads();
  // stage A: raw F -> LDS (pair m holds F0 at SW(k), F1 at SW(256+k))
  for (int it = 0; it < 8; ++it) {
    int e = tid + (it << 8);
    int k = e >> 3, rr = e & 7;
    int m = rr >> 1, p = rr & 1;
    s[m][SW(k + 256 * p)] = Tb[(size_t)k * NRHO + i0 + rr];
  }
  __syncthreads();
  // stage B: build Z = F0 + i*F1 over k=0..511 (registers to avoid in-place hazard)
  float2 Zr[8];
  for (int it = 0; it < 8; ++it) {
    int e = tid + (it << 8);
    int m = e >> 9, k = e & 511;
    float2 z;
    if (k == 256) z = make_float2(0.f, 0.f);
    else {
      int k2 = (k < 256) ? k : 512 - k;
      float2 F0 = s[m][SW(k2)];
      float2 F1 = s[m][SW(256 + k2)];
      if (k2 == 0) { F0.y = 0.f; F1.y = 0.f; }       // numpy irfft ignores DC imag
      if (k < 256) z = make_float2(F0.x - F1.y, F0.y + F1.x);
      else         z = make_float2(F0.x + F1.y, F1.x - F0.y);
    }
    Zr[it] = z;
  }
  __syncthreads();
  for (int it = 0; it < 8; ++it) {
    int e = tid + (it << 8);
    int m = e >> 9, k = e & 511;
    s[m][SW(k)] = Zr[it];
  }
  // inverse DIF (sign +): natural in -> bit-reversed out
  for (int lh = 8; lh >= 0; --lh) {
    __syncthreads();
    for (int it = 0; it < 4; ++it) {
      int e = tid + (it << 8);
      int m = e >> 8, b = e & 255;
      int pos = b & ((1 << lh) - 1);
      int ia  = ((b >> lh) << (lh + 1)) | pos;
      float2 w = twl[pos << (8 - lh)];
      float2* sm = s[m];
      float2 u = sm[SW(ia)];
      float2 v = sm[SW(ia + (1 << lh))];
      sm[SW(ia)] = make_float2(u.x + v.x, u.y + v.y);
      float2 d = make_float2(u.x - v.x, u.y - v.y);
      sm[SW(ia + (1 << lh))] = cmulcf(d, w);
    }
  }
  __syncthreads();
  // write ALL 512 theta slots x 8 rho cols (4096 values)
  float* gb = gkT + (size_t)(span * gridDim.y + lb) * (NTH * NRHO);
  for (int it = 0; it < 16; ++it) {
    int e = tid + (it << 8);                         // 0..4095
    int jslot = e >> 3, rr = e & 7;
    float2 z = s[rr >> 1][SW(jslot)];
    gb[(size_t)jslot * NRHO + i0 + rr] = (rr & 1) ? z.y : z.x;
  }
}

// ---------------- resample to (angle, det), ALL spans in one dispatch ----------------
// Span of angle t: k = (3t)>>10 (exact partition; boundaries never integral).
__global__ __launch_bounds__(256) void k_scatter(const float* __restrict__ gkT,
                                                 float* __restrict__ out,
                                                 int b0, int chunk,
                                                 double d_rho, double aR) {
  int p = blockIdx.x * 256 + threadIdx.x;
  if (p >= PTOT) return;
  const int t = p >> 9;
  const int d = p & 511;
  const int span = (3 * t) >> 10;
  const double beta = M_PI / 3.0;
  double th0 = (double)t * M_PI / 1024.0 - beta / 2.0;
  double th00 = th0 - (double)span * beta;
  double d_th = 2.0 * beta / 512.0;
  double th_lp0 = -256.0 * d_th, th_lpL = 255.0 * d_th;
  double p1 = (th00 - th_lp0) / (th_lpL - th_lp0) * 511.0;
  double s0v = (d == 511) ? 1.0 : (double)d * (2.0 / 511.0) - 1.0;
  double p2 = log(s0v * aR + (1.0 - aR) * cos(th00));
  double rho0 = -1024.0 * d_rho, rhoL = -1.0 * d_rho;
  p2 = (p2 - rho0) / (rhoL - rho0) * 1023.0;
  double fy = floor(p2); fy = fy < 0.0 ? 0.0 : (fy > 1022.0 ? 1022.0 : fy);
  double fx = floor(p1); fx = fx < 0.0 ? 0.0 : (fx > 510.0 ? 510.0 : fx);
  int row = __brev((unsigned)(int)fx) >> 23;         // bit-reversed theta row
  int idx = row * 1024 + (int)fy;
  const float* gsp = gkT + (size_t)span * chunk * (NTH * NRHO);
  for (int lb = 0; lb < chunk; ++lb)
    out[(size_t)(b0 + lb) * PTOT + p] = gsp[(size_t)lb * (NTH * NRHO) + idx];
}

// ---------------- launch ----------------
extern "C" void kernel_launch(void* const* d_in, const int* in_sizes, int n_in,
                              void* d_out, int out_size, void* d_ws, size_t ws_size,
                              hipStream_t stream) {
  (void)n_in; (void)out_size;
  const float* x = (const float*)d_in[0];
  float* out = (float*)d_out;
  const int batch = in_sizes[0] / (NIMG * NIMG);

  const size_t zeta_b = (size_t)ZROWS * NRHO * sizeof(float2);          // 2 MB
  const size_t idx_b  = (size_t)NSPAN * NRHO * NTH * sizeof(int);       // 6 MB
  const size_t tab_b  = 2048 * sizeof(double) * 2 + 1024 * sizeof(float2) * 2;
  const size_t per_b  = (size_t)NSPAN * ((size_t)ZROWS * NRHO * sizeof(float2)
                      + (size_t)NTH * NRHO * sizeof(float));            // 12 MB / image
  int chunk = batch;
  while (chunk > 1 && zeta_b + idx_b + tab_b + (size_t)chunk * per_b > ws_size) chunk >>= 1;

  char* ws = (char*)d_ws;
  float2* zetaT   = (float2*)ws;  ws += zeta_b;
  int*    idx1    = (int*)ws;     ws += idx_b;
  double* Ltab    = (double*)ws;  ws += 2048 * sizeof(double);
  double* amp     = (double*)ws;  ws += 2048 * sizeof(double);
  float2* tw1024f = (float2*)ws;  ws += 1024 * sizeof(float2);
  float2* tw2048f = (float2*)ws;  ws += 1024 * sizeof(float2);
  float2* T       = (float2*)ws;  ws += (size_t)NSPAN * chunk * ZROWS * NRHO * sizeof(float2);
  float*  gkT     = (float*)ws;

  k_pre     <<<dim3(8),    dim3(256), 0, stream>>>(Ltab, amp, tw1024f, tw2048f);
  k_zeta    <<<dim3(1024), dim3(256), 0, stream>>>(Ltab, amp, tw2048f, zetaT,
                                                   g_C.G_LA, g_C.dth, g_C.constv);
  k_idx_lp2c<<<dim3((NSPAN * NRHO * NTH) / 256), dim3(256), 0, stream>>>(idx1, g_C.d_rho, g_C.aR);

  for (int b0 = 0; b0 < batch; b0 += chunk) {
    int c = (b0 + chunk <= batch) ? chunk : (batch - b0);
    k_gather_rfft<<<dim3(NRHO / 8, c, NSPAN), dim3(256), 0, stream>>>(x, idx1, tw1024f, T, b0, g_C.d_rho);
    k_fft_rho    <<<dim3(ZROWS,   c, NSPAN), dim3(256), 0, stream>>>(T, zetaT, tw1024f);
    k_irfft_th   <<<dim3(NRHO / 8, c, NSPAN), dim3(256), 0, stream>>>(T, tw1024f, gkT);
    k_scatter    <<<dim3(PTOT / 256), dim3(256), 0, stream>>>(gkT, out, b0, c,
                                                              g_C.d_rho, g_C.aR);
  }
}

// Round 8
// 317.320 us; speedup vs baseline: 2.8734x; 1.0069x over previous
//
#include <hip/hip_runtime.h>
#include <cmath>

#ifndef M_PI
#define M_PI 3.14159265358979323846
#endif

#define NIMG 512
#define NRHO 1024
#define NTH  512
#define ZROWS 256           // theta bins kept (bin 256 zeroed by zeta -> dropped)
#define S4   520            // LDS row stride (float2) for 4-row pair kernels
#define PTOT (1024*512)     // n_angles * n_det
#define NSPAN 3

// ---------------- host-side scalar constants ----------------
struct Consts { double G_LA, d_rho, aR, dth, constv; };

static Consts compute_consts() {
  Consts c;
  const double beta = M_PI / 3.0;
  const double sb = sin(beta / 2.0), cb = cos(beta / 2.0);
  const double aR = sb / (1.0 + sb);
  const double am = (cb - sb) / (1.0 + sb);
  double g = -1e300;
  const double start = -M_PI / 2.0, stop = M_PI / 2.0;
  const double delta = (stop - start) / 999.0;
  for (int i = 0; i < 1000; ++i) {
    double t = (i == 999) ? stop : (double)i * delta + start;
    double wre = aR * cos(t) + (1.0 - aR);
    double wim = aR * sin(t);
    double v = log(hypot(wre, wim)) + log(cos(beta / 2.0 - atan2(wim, wre)));
    if (!std::isnan(v) && v > g) g = v;
  }
  c.aR    = aR;
  c.G_LA  = g - log(am);
  c.d_rho = c.G_LA / 1024.0;
  double t1 = (-1023.0 / 2048.0) * beta * 2.0;
  double t0 = (-1024.0 / 2048.0) * beta * 2.0;
  c.dth = t1 - t0;
  c.constv = sqrt(0.5) * M_PI / 4.0 / aR / sqrt(2.0);
  return c;
}
static const Consts g_C = compute_consts();

// ---------------- device helpers ----------------
__device__ __forceinline__ float2 cmulf(float2 a, float2 b) {
  return make_float2(a.x * b.x - a.y * b.y, a.x * b.y + a.y * b.x);
}
__device__ __forceinline__ float2 cmulcf(float2 a, float2 w) {   // a * conj(w)
  return make_float2(a.x * w.x + a.y * w.y, a.y * w.x - a.x * w.y);
}
__device__ __forceinline__ int SW(int i) { return i ^ ((i >> 5) & 31); }  // XOR bank swizzle
__device__ __forceinline__ int PD(int i) { return i + (i >> 4); }         // pad-per-16 permutation
__device__ __forceinline__ int dr4_10(int v) {                    // reverse 5 base-4 digits
  int r = 0;
  #pragma unroll
  for (int k = 0; k < 5; ++k) { r = (r << 2) | (v & 3); v >>= 2; }
  return r;
}
__device__ __forceinline__ double h_val(int jj) {
  const double ctab[11] = {-216254335.0, 679543284.0, -1412947389.0, 2415881496.0,
                           -3103579086.0, 2939942400.0, -2023224114.0, 984515304.0,
                           -321455811.0, 63253516.0, -5675265.0};
  int j = -1;
  if (jj <= 10) j = jj;
  else if (jj >= 2038) j = 2048 - jj;
  if (j < 0) return 1.0;
  double c = 1.0 + ctab[j] / 958003200.0;
  if (j == 0) c = 2.0 * (c - 0.5);
  return c;
}

// ---------------- precompute: L/amp tables + fp32 twiddle tables ----------------
__global__ __launch_bounds__(256) void k_pre(double* __restrict__ Ltab,
                                             double* __restrict__ amp,
                                             float2* __restrict__ tw1024f,
                                             float2* __restrict__ tw2048f) {
  int id = blockIdx.x * 256 + threadIdx.x;
  const double beta = M_PI / 3.0;
  if (id < 2048) {
    double th = ((double)(id - 1024) / 2048.0) * beta * 2.0;
    double L = log(cos(th));
    Ltab[id] = L;
    amp[id]  = h_val(id) * exp(-L);
  }
  if (id < 1024) {
    double a1 = -2.0 * M_PI * (double)id / 1024.0;
    double a2 = -2.0 * M_PI * (double)id / 2048.0;
    double s1, c1, s2, c2;
    sincos(a1, &s1, &c1); sincos(a2, &s2, &c2);
    tw1024f[id] = make_float2((float)c1, (float)s1);
    tw2048f[id] = make_float2((float)c2, (float)s2);
  }
}

// ---------------- zeta: fp32 2048-pt FFT per rho-frequency row ----------------
// zetaT[j][p], j<256 theta bin, p = base-4-digit-reversed rho freq.
// Includes const*dth/b3 and both inverse-FFT normalizations.
__global__ __launch_bounds__(256) void k_zeta(const double* __restrict__ Ltab,
                                              const double* __restrict__ amp,
                                              const float2* __restrict__ tw2048f,
                                              float2* __restrict__ zetaT,
                                              double G_LA, double dth, double constv) {
  __shared__ float2 s[2048 + 128];
  __shared__ float2 twl[1024 + 64];
  const int i   = blockIdx.x;    // k_rho row 0..1023
  const int tid = threadIdx.x;
  for (int e = tid; e < 1024; e += 256) twl[PD(e)] = tw2048f[e];
  const double om = 2.0 * M_PI * (double)(i - 512) / G_LA;
  const double INV2PI = 1.0 / (2.0 * M_PI);
  for (int j = tid; j < 2048; j += 256) {
    int jj = (j + 1024) & 2047;
    double ph = -om * Ltab[jj] * INV2PI;
    ph -= floor(ph);
    float ang = (float)ph * 6.28318530717958647f;
    float sv, cv; __sincosf(ang, &sv, &cv);
    float a = (float)amp[jj];
    s[PD(__brev((unsigned)j) >> 21)] = make_float2(a * cv, a * sv);
  }
  for (int lh = 0; lh < 11; ++lh) {
    __syncthreads();
    for (int e = tid; e < 1024; e += 256) {
      int pos = e & ((1 << lh) - 1);
      int ia  = ((e >> lh) << (lh + 1)) | pos;
      float2 w = twl[PD(pos << (10 - lh))];
      float2 u = s[PD(ia)];
      float2 v = cmulf(s[PD(ia + (1 << lh))], w);
      s[PD(ia)]             = make_float2(u.x + v.x, u.y + v.y);
      s[PD(ia + (1 << lh))] = make_float2(u.x - v.x, u.y - v.y);
    }
  }
  __syncthreads();
  const int i2 = (i + 512) & 1023;
  const int p  = dr4_10(i2);
  const double b3r = (4.0 + 2.0 * cos(2.0 * M_PI * (double)i2 / 1024.0)) / 6.0;
  if (tid < 256) {
    int j2 = tid;
    float2 z = make_float2(0.f, 0.f);
    if (i != 0) {
      float2 F = s[PD(j2)];
      double b3t = (4.0 + 2.0 * cos(2.0 * M_PI * (double)j2 / 512.0)) / 6.0;
      double sc = dth * constv / (b3r * b3t) * (1.0 / (1024.0 * 512.0));
      z = make_float2((float)((double)F.x * sc), (float)((double)F.y * sc));
    }
    zetaT[(size_t)j2 * 1024 + p] = z;
  }
}

// ---------------- gather index map, ALL spans, natural theta order ----------------
__global__ __launch_bounds__(256) void k_idx_lp2c(int* __restrict__ idx1,
                                                  double d_rho, double aR) {
  int q = blockIdx.x * 256 + threadIdx.x;
  int span = q >> 19;                                // q / (NRHO*NTH)
  int ql = q & (NRHO * NTH - 1);
  int i = ql >> 9, j = ql & 511;
  const double beta = M_PI / 3.0;
  double d_th = 2.0 * beta / 512.0;
  double th = (double)(j - 256) * d_th;
  double er = exp((double)(i - 1024) * d_rho);
  double t1 = er * cos(th), t2 = er * sin(th);
  double a = (double)span * beta + beta / 2.0;
  double ca = cos(a), sa = sin(a);
  double l1 = ((t1 - (1.0 - aR)) * ca - t2 * sa) / aR;
  double l2 = -(((t1 - (1.0 - aR)) * sa + t2 * ca) / aR);
  l1 = (l1 + 1.0) / 2.0 * 511.0;
  l2 = (l2 + 1.0) / 2.0 * 511.0;
  double fy = floor(l1); fy = fy < 0.0 ? 0.0 : (fy > 510.0 ? 510.0 : fy);
  double fx = floor(l2); fx = fx < 0.0 ? 0.0 : (fx > 510.0 ? 510.0 : fx);
  idx1[q] = (int)fy * 512 + (int)fx;
}

// ---------------- gather + paired rfft(512): 8 rho-rows = 4 complex FFTs ----------------
// blockIdx.z = span. Thread tid: rho row r=tid>>5, 16 consecutive theta.
__global__ __launch_bounds__(256) void k_gather_rfft(const float* __restrict__ x,
                                                     const int* __restrict__ idx1,
                                                     const float2* __restrict__ tw1024f,
                                                     float2* __restrict__ T,
                                                     int b0, double d_rho) {
  __shared__ float2 s[4][S4];     // 16.6 KB
  __shared__ float2 twl[256];
  const int bx   = blockIdx.x;
  const int g    = ((bx & 7) << 4) | (bx >> 3);      // XCD ring swizzle (128 blocks)
  const int i0   = g * 8;
  const int lb   = blockIdx.y;
  const int span = blockIdx.z;
  const int tid  = threadIdx.x;
  twl[tid] = tw1024f[2 * tid];                       // exp(-2pi i m/512), m<256
  const int r  = tid >> 5;                           // rho row 0..7
  const int t5 = tid & 31;
  const float er = (float)exp((double)(i0 + r - 1024) * d_rho);
  const float* xb = x + (size_t)(b0 + lb) * (NIMG * NIMG);
  const int4* ip = (const int4*)(idx1 + span * (NRHO * NTH) + (i0 + r) * 512 + t5 * 16);
  int4 i4[4];
  #pragma unroll
  for (int u = 0; u < 4; ++u) i4[u] = ip[u];
  float v[16];
  #pragma unroll
  for (int u = 0; u < 4; ++u) {                      // 16 gathers issued back-to-back
    v[4 * u + 0] = xb[i4[u].x];
    v[4 * u + 1] = xb[i4[u].y];
    v[4 * u + 2] = xb[i4[u].z];
    v[4 * u + 3] = xb[i4[u].w];
  }
  float* sm = (float*)s[r >> 1];
  const int p = r & 1;
  #pragma unroll
  for (int u = 0; u < 16; ++u) {
    int j = t5 * 16 + u;
    int slot = __brev((unsigned)j) >> 23;            // bit-reversal for free
    sm[2 * SW(slot) + p] = v[u] * er;
  }
  // 4 complex FFT-512, radix-2 DIT (input bit-reversed, output natural)
  for (int lh = 0; lh < 9; ++lh) {
    __syncthreads();
    for (int it = 0; it < 4; ++it) {
      int e = tid + (it << 8);
      int m = e >> 8, b = e & 255;
      int pos = b & ((1 << lh) - 1);
      int ia  = ((b >> lh) << (lh + 1)) | pos;
      float2 w = twl[pos << (8 - lh)];
      float2* smm = s[m];
      float2 u = smm[SW(ia)];
      float2 vv = cmulf(smm[SW(ia + (1 << lh))], w);
      smm[SW(ia)]             = make_float2(u.x + vv.x, u.y + vv.y);
      smm[SW(ia + (1 << lh))] = make_float2(u.x - vv.x, u.y - vv.y);
    }
  }
  __syncthreads();
  // unpack pair spectra + transposed coalesced write (64B per theta bin)
  float2* Tb = T + (size_t)(span * gridDim.y + lb) * (ZROWS * NRHO);
  for (int it = 0; it < 8; ++it) {
    int e = tid + (it << 8);                         // 0..2047
    int k = e >> 3, rr = e & 7;
    int m = rr >> 1, pp = rr & 1;
    float2 Z  = s[m][SW(k)];
    float2 Zc = s[m][SW((512 - k) & 511)];
    float2 F;
    if (!pp) F = make_float2(0.5f * (Z.x + Zc.x), 0.5f * (Z.y - Zc.y));
    else     F = make_float2(0.5f * (Z.y + Zc.y), 0.5f * (Zc.x - Z.x));
    Tb[(size_t)k * NRHO + i0 + rr] = F;
  }
}

// ---------------- rho: fft1024 * zeta * ifft1024, radix-4, one theta-bin/block ----------------
// LDS indices pass through PD() pad-permutation: 4-way worst-case banks vs 16-way raw.
__global__ __launch_bounds__(256) void k_fft_rho(float2* __restrict__ T,
                                                 const float2* __restrict__ zetaT,
                                                 const float2* __restrict__ tw1024f) {
  __shared__ float2 s[1024 + 64];
  __shared__ float2 twl[1024 + 64];
  const int j    = blockIdx.x;
  const int lb   = blockIdx.y;
  const int span = blockIdx.z;
  const int tid  = threadIdx.x;
  for (int e = tid; e < 1024; e += 256) twl[PD(e)] = tw1024f[e];
  float2* row = T + ((size_t)(span * gridDim.y + lb) * ZROWS + j) * NRHO;
  {
    const float4* rp = (const float4*)row;
    for (int e = tid; e < 512; e += 256) {
      float4 v = rp[e];
      s[PD(2 * e)]     = make_float2(v.x, v.y);
      s[PD(2 * e + 1)] = make_float2(v.z, v.w);
    }
  }
  __syncthreads();
  #pragma unroll
  for (int lq = 8; lq >= 0; lq -= 2) {
    const int q = 1 << lq, tfac = 256 >> lq;
    int jj = tid & (q - 1);
    int base = ((tid >> lq) << (lq + 2)) | jj;
    float2 a = s[PD(base)], b = s[PD(base + q)];
    float2 c = s[PD(base + 2 * q)], d = s[PD(base + 3 * q)];
    float2 A = make_float2(a.x + c.x, a.y + c.y);
    float2 C = make_float2(a.x - c.x, a.y - c.y);
    float2 B = make_float2(b.x + d.x, b.y + d.y);
    float2 D = make_float2(b.x - d.x, b.y - d.y);
    float2 u0 = make_float2(A.x + B.x, A.y + B.y);
    float2 u2 = make_float2(A.x - B.x, A.y - B.y);
    float2 u1 = make_float2(C.x + D.y, C.y - D.x);
    float2 u3 = make_float2(C.x - D.y, C.y + D.x);
    int t1i = jj * tfac;
    s[PD(base)]         = u0;
    s[PD(base + q)]     = cmulf(u1, twl[PD(t1i)]);
    s[PD(base + 2 * q)] = cmulf(u2, twl[PD(2 * t1i)]);
    s[PD(base + 3 * q)] = cmulf(u3, twl[PD(3 * t1i)]);
    __syncthreads();
  }
  {
    const float2* zrow = zetaT + (size_t)j * NRHO;
    for (int e = tid; e < 1024; e += 256)
      s[PD(e)] = cmulf(s[PD(e)], zrow[e]);
  }
  __syncthreads();
  #pragma unroll
  for (int lq = 0; lq <= 8; lq += 2) {
    const int q = 1 << lq, tfac = 256 >> lq;
    int jj = tid & (q - 1);
    int base = ((tid >> lq) << (lq + 2)) | jj;
    int t1i = jj * tfac;
    float2 u0 = s[PD(base)];
    float2 u1 = cmulcf(s[PD(base + q)],     twl[PD(t1i)]);
    float2 u2 = cmulcf(s[PD(base + 2 * q)], twl[PD(2 * t1i)]);
    float2 u3 = cmulcf(s[PD(base + 3 * q)], twl[PD(3 * t1i)]);
    float2 t0 = make_float2(u0.x + u2.x, u0.y + u2.y);
    float2 t1 = make_float2(u0.x - u2.x, u0.y - u2.y);
    float2 t2 = make_float2(u1.x + u3.x, u1.y + u3.y);
    float2 t3 = make_float2(u1.x - u3.x, u1.y - u3.y);
    s[PD(base)]         = make_float2(t0.x + t2.x, t0.y + t2.y);
    s[PD(base + 2 * q)] = make_float2(t0.x - t2.x, t0.y - t2.y);
    s[PD(base + q)]     = make_float2(t1.x - t3.y, t1.y + t3.x);
    s[PD(base + 3 * q)] = make_float2(t1.x + t3.y, t1.y - t3.x);
    __syncthreads();
  }
  {
    float4* rp = (float4*)row;
    for (int e = tid; e < 512; e += 256) {
      float2 a = s[PD(2 * e)], b = s[PD(2 * e + 1)];
      rp[e] = make_float4(a.x, a.y, b.x, b.y);
    }
  }
}

// ---------------- paired Hermitian irfft(512): 8 rho-rows = 4 complex IFFTs ----------------
// Output gkT rows are in BIT-REVERSED theta order (scatter compensates).
__global__ __launch_bounds__(256) void k_irfft_th(const float2* __restrict__ T,
                                                  const float2* __restrict__ tw1024f,
                                                  float* __restrict__ gkT) {
  __shared__ float2 s[4][S4];
  __shared__ float2 twl[256];
  const int i0   = blockIdx.x * 8;
  const int lb   = blockIdx.y;
  const int span = blockIdx.z;
  const int tid  = threadIdx.x;
  twl[tid] = tw1024f[2 * tid];
  const float2* Tb = T + (size_t)(span * gridDim.y + lb) * (ZROWS * NRHO);
  __syncthreads();
  // stage A: raw F -> LDS (pair m holds F0 at SW(k), F1 at SW(256+k))
  for (int it = 0; it < 8; ++it) {
    int e = tid + (it << 8);
    int k = e >> 3, rr = e & 7;
    int m = rr >> 1, p = rr & 1;
    s[m][SW(k + 256 * p)] = Tb[(size_t)k * NRHO + i0 + rr];
  }
  __syncthreads();
  // stage B: build Z = F0 + i*F1 over k=0..511 (registers to avoid in-place hazard)
  float2 Zr[8];
  for (int it = 0; it < 8; ++it) {
    int e = tid + (it << 8);
    int m = e >> 9, k = e & 511;
    float2 z;
    if (k == 256) z = make_float2(0.f, 0.f);
    else {
      int k2 = (k < 256) ? k : 512 - k;
      float2 F0 = s[m][SW(k2)];
      float2 F1 = s[m][SW(256 + k2)];
      if (k2 == 0) { F0.y = 0.f; F1.y = 0.f; }       // numpy irfft ignores DC imag
      if (k < 256) z = make_float2(F0.x - F1.y, F0.y + F1.x);
      else         z = make_float2(F0.x + F1.y, F1.x - F0.y);
    }
    Zr[it] = z;
  }
  __syncthreads();
  for (int it = 0; it < 8; ++it) {
    int e = tid + (it << 8);
    int m = e >> 9, k = e & 511;
    s[m][SW(k)] = Zr[it];
  }
  // inverse DIF (sign +): natural in -> bit-reversed out
  for (int lh = 8; lh >= 0; --lh) {
    __syncthreads();
    for (int it = 0; it < 4; ++it) {
      int e = tid + (it << 8);
      int m = e >> 8, b = e & 255;
      int pos = b & ((1 << lh) - 1);
      int ia  = ((b >> lh) << (lh + 1)) | pos;
      float2 w = twl[pos << (8 - lh)];
      float2* sm = s[m];
      float2 u = sm[SW(ia)];
      float2 v = sm[SW(ia + (1 << lh))];
      sm[SW(ia)] = make_float2(u.x + v.x, u.y + v.y);
      float2 d = make_float2(u.x - v.x, u.y - v.y);
      sm[SW(ia + (1 << lh))] = cmulcf(d, w);
    }
  }
  __syncthreads();
  // write ALL 512 theta slots x 8 rho cols (4096 values)
  float* gb = gkT + (size_t)(span * gridDim.y + lb) * (NTH * NRHO);
  for (int it = 0; it < 16; ++it) {
    int e = tid + (it << 8);                         // 0..4095
    int jslot = e >> 3, rr = e & 7;
    float2 z = s[rr >> 1][SW(jslot)];
    gb[(size_t)jslot * NRHO + i0 + rr] = (rr & 1) ? z.y : z.x;
  }
}

// ---------------- resample to (angle, det), ALL spans in one dispatch ----------------
// Span of angle t: k = (3t)>>10 (exact partition; boundaries never integral).
__global__ __launch_bounds__(256) void k_scatter(const float* __restrict__ gkT,
                                                 float* __restrict__ out,
                                                 int b0, int chunk,
                                                 double d_rho, double aR) {
  int p = blockIdx.x * 256 + threadIdx.x;
  if (p >= PTOT) return;
  const int t = p >> 9;
  const int d = p & 511;
  const int span = (3 * t) >> 10;
  const double beta = M_PI / 3.0;
  double th0 = (double)t * M_PI / 1024.0 - beta / 2.0;
  double th00 = th0 - (double)span * beta;
  double d_th = 2.0 * beta / 512.0;
  double th_lp0 = -256.0 * d_th, th_lpL = 255.0 * d_th;
  double p1 = (th00 - th_lp0) / (th_lpL - th_lp0) * 511.0;
  double s0v = (d == 511) ? 1.0 : (double)d * (2.0 / 511.0) - 1.0;
  double p2 = log(s0v * aR + (1.0 - aR) * cos(th00));
  double rho0 = -1024.0 * d_rho, rhoL = -1.0 * d_rho;
  p2 = (p2 - rho0) / (rhoL - rho0) * 1023.0;
  double fy = floor(p2); fy = fy < 0.0 ? 0.0 : (fy > 1022.0 ? 1022.0 : fy);
  double fx = floor(p1); fx = fx < 0.0 ? 0.0 : (fx > 510.0 ? 510.0 : fx);
  int row = __brev((unsigned)(int)fx) >> 23;         // bit-reversed theta row
  int idx = row * 1024 + (int)fy;
  const float* gsp = gkT + (size_t)span * chunk * (NTH * NRHO);
  for (int lb = 0; lb < chunk; ++lb)
    out[(size_t)(b0 + lb) * PTOT + p] = gsp[(size_t)lb * (NTH * NRHO) + idx];
}

// ---------------- launch ----------------
extern "C" void kernel_launch(void* const* d_in, const int* in_sizes, int n_in,
                              void* d_out, int out_size, void* d_ws, size_t ws_size,
                              hipStream_t stream) {
  (void)n_in; (void)out_size;
  const float* x = (const float*)d_in[0];
  float* out = (float*)d_out;
  const int batch = in_sizes[0] / (NIMG * NIMG);

  const size_t zeta_b = (size_t)ZROWS * NRHO * sizeof(float2);          // 2 MB
  const size_t idx_b  = (size_t)NSPAN * NRHO * NTH * sizeof(int);       // 6 MB
  const size_t tab_b  = 2048 * sizeof(double) * 2 + 1024 * sizeof(float2) * 2;
  const size_t per_b  = (size_t)NSPAN * ((size_t)ZROWS * NRHO * sizeof(float2)
                      + (size_t)NTH * NRHO * sizeof(float));            // 12 MB / image
  int chunk = batch;
  while (chunk > 1 && zeta_b + idx_b + tab_b + (size_t)chunk * per_b > ws_size) chunk >>= 1;

  char* ws = (char*)d_ws;
  float2* zetaT   = (float2*)ws;  ws += zeta_b;
  int*    idx1    = (int*)ws;     ws += idx_b;
  double* Ltab    = (double*)ws;  ws += 2048 * sizeof(double);
  double* amp     = (double*)ws;  ws += 2048 * sizeof(double);
  float2* tw1024f = (float2*)ws;  ws += 1024 * sizeof(float2);
  float2* tw2048f = (float2*)ws;  ws += 1024 * sizeof(float2);
  float2* T       = (float2*)ws;  ws += (size_t)NSPAN * chunk * ZROWS * NRHO * sizeof(float2);
  float*  gkT     = (float*)ws;

  k_pre     <<<dim3(8),    dim3(256), 0, stream>>>(Ltab, amp, tw1024f, tw2048f);
  k_zeta    <<<dim3(1024), dim3(256), 0, stream>>>(Ltab, amp, tw2048f, zetaT,
                                                   g_C.G_LA, g_C.dth, g_C.constv);
  k_idx_lp2c<<<dim3((NSPAN * NRHO * NTH) / 256), dim3(256), 0, stream>>>(idx1, g_C.d_rho, g_C.aR);

  for (int b0 = 0; b0 < batch; b0 += chunk) {
    int c = (b0 + chunk <= batch) ? chunk : (batch - b0);
    k_gather_rfft<<<dim3(NRHO / 8, c, NSPAN), dim3(256), 0, stream>>>(x, idx1, tw1024f, T, b0, g_C.d_rho);
    k_fft_rho    <<<dim3(ZROWS,   c, NSPAN), dim3(256), 0, stream>>>(T, zetaT, tw1024f);
    k_irfft_th   <<<dim3(NRHO / 8, c, NSPAN), dim3(256), 0, stream>>>(T, tw1024f, gkT);
    k_scatter    <<<dim3(PTOT / 256), dim3(256), 0, stream>>>(gkT, out, b0, c,
                                                              g_C.d_rho, g_C.aR);
  }
}

// Round 10
// 286.018 us; speedup vs baseline: 3.1878x; 1.1094x over previous
//
#include <hip/hip_runtime.h>
#include <cmath>

#ifndef M_PI
#define M_PI 3.14159265358979323846
#endif

#define NIMG 512
#define NRHO 1024
#define NTH  512
#define ZROWS 256           // theta bins kept (bin 256 zeroed by zeta -> dropped)
#define GROWS 256           // gk theta rows kept: fx in [128,384) only
#define S4   520            // LDS row stride (float2) for 4-row pair kernels
#define PTOT (1024*512)     // n_angles * n_det
#define NSPAN 3

// ---------------- host-side scalar constants ----------------
struct Consts { double G_LA, d_rho, aR, dth, constv; };

static Consts compute_consts() {
  Consts c;
  const double beta = M_PI / 3.0;
  const double sb = sin(beta / 2.0), cb = cos(beta / 2.0);
  const double aR = sb / (1.0 + sb);
  const double am = (cb - sb) / (1.0 + sb);
  double g = -1e300;
  const double start = -M_PI / 2.0, stop = M_PI / 2.0;
  const double delta = (stop - start) / 999.0;
  for (int i = 0; i < 1000; ++i) {
    double t = (i == 999) ? stop : (double)i * delta + start;
    double wre = aR * cos(t) + (1.0 - aR);
    double wim = aR * sin(t);
    double v = log(hypot(wre, wim)) + log(cos(beta / 2.0 - atan2(wim, wre)));
    if (!std::isnan(v) && v > g) g = v;
  }
  c.aR    = aR;
  c.G_LA  = g - log(am);
  c.d_rho = c.G_LA / 1024.0;
  double t1 = (-1023.0 / 2048.0) * beta * 2.0;
  double t0 = (-1024.0 / 2048.0) * beta * 2.0;
  c.dth = t1 - t0;
  c.constv = sqrt(0.5) * M_PI / 4.0 / aR / sqrt(2.0);
  return c;
}
static const Consts g_C = compute_consts();

// ---------------- device helpers ----------------
__device__ __forceinline__ float2 cmulf(float2 a, float2 b) {
  return make_float2(a.x * b.x - a.y * b.y, a.x * b.y + a.y * b.x);
}
__device__ __forceinline__ float2 cmulcf(float2 a, float2 w) {   // a * conj(w)
  return make_float2(a.x * w.x + a.y * w.y, a.y * w.x - a.x * w.y);
}
__device__ __forceinline__ int SW(int i) { return i ^ ((i >> 5) & 31); }  // XOR bank swizzle
__device__ __forceinline__ int PD(int i) { return i + (i >> 4); }         // pad-per-16 permutation
__device__ __forceinline__ int dr4_10(int v) {                    // reverse 5 base-4 digits
  int r = 0;
  #pragma unroll
  for (int k = 0; k < 5; ++k) { r = (r << 2) | (v & 3); v >>= 2; }
  return r;
}
__device__ __forceinline__ double h_val(int jj) {
  const double ctab[11] = {-216254335.0, 679543284.0, -1412947389.0, 2415881496.0,
                           -3103579086.0, 2939942400.0, -2023224114.0, 984515304.0,
                           -321455811.0, 63253516.0, -5675265.0};
  int j = -1;
  if (jj <= 10) j = jj;
  else if (jj >= 2038) j = 2048 - jj;
  if (j < 0) return 1.0;
  double c = 1.0 + ctab[j] / 958003200.0;
  if (j == 0) c = 2.0 * (c - 0.5);
  return c;
}

// ---------------- precompute: L/amp tables + fp32 twiddle tables ----------------
__global__ __launch_bounds__(256) void k_pre(double* __restrict__ Ltab,
                                             double* __restrict__ amp,
                                             float2* __restrict__ tw1024f,
                                             float2* __restrict__ tw2048f) {
  int id = blockIdx.x * 256 + threadIdx.x;
  const double beta = M_PI / 3.0;
  if (id < 2048) {
    double th = ((double)(id - 1024) / 2048.0) * beta * 2.0;
    double L = log(cos(th));
    Ltab[id] = L;
    amp[id]  = h_val(id) * exp(-L);
  }
  if (id < 1024) {
    double a1 = -2.0 * M_PI * (double)id / 1024.0;
    double a2 = -2.0 * M_PI * (double)id / 2048.0;
    double s1, c1, s2, c2;
    sincos(a1, &s1, &c1); sincos(a2, &s2, &c2);
    tw1024f[id] = make_float2((float)c1, (float)s1);
    tw2048f[id] = make_float2((float)c2, (float)s2);
  }
}

// ---------------- zeta: fp32 2048-pt FFT per rho-frequency row ----------------
// zetaT[j][p], j<256 theta bin, p = base-4-digit-reversed rho freq.
// Includes const*dth/b3 and both inverse-FFT normalizations.
__global__ __launch_bounds__(256) void k_zeta(const double* __restrict__ Ltab,
                                              const double* __restrict__ amp,
                                              const float2* __restrict__ tw2048f,
                                              float2* __restrict__ zetaT,
                                              double G_LA, double dth, double constv) {
  __shared__ float2 s[2048 + 128];
  __shared__ float2 twl[1024 + 64];
  const int i   = blockIdx.x;    // k_rho row 0..1023
  const int tid = threadIdx.x;
  for (int e = tid; e < 1024; e += 256) twl[PD(e)] = tw2048f[e];
  const double om = 2.0 * M_PI * (double)(i - 512) / G_LA;
  const double INV2PI = 1.0 / (2.0 * M_PI);
  for (int j = tid; j < 2048; j += 256) {
    int jj = (j + 1024) & 2047;
    double ph = -om * Ltab[jj] * INV2PI;
    ph -= floor(ph);
    float ang = (float)ph * 6.28318530717958647f;
    float sv, cv; __sincosf(ang, &sv, &cv);
    float a = (float)amp[jj];
    s[PD(__brev((unsigned)j) >> 21)] = make_float2(a * cv, a * sv);
  }
  for (int lh = 0; lh < 11; ++lh) {
    __syncthreads();
    for (int e = tid; e < 1024; e += 256) {
      int pos = e & ((1 << lh) - 1);
      int ia  = ((e >> lh) << (lh + 1)) | pos;
      float2 w = twl[PD(pos << (10 - lh))];
      float2 u = s[PD(ia)];
      float2 v = cmulf(s[PD(ia + (1 << lh))], w);
      s[PD(ia)]             = make_float2(u.x + v.x, u.y + v.y);
      s[PD(ia + (1 << lh))] = make_float2(u.x - v.x, u.y - v.y);
    }
  }
  __syncthreads();
  const int i2 = (i + 512) & 1023;
  const int p  = dr4_10(i2);
  const double b3r = (4.0 + 2.0 * cos(2.0 * M_PI * (double)i2 / 1024.0)) / 6.0;
  if (tid < 256) {
    int j2 = tid;
    float2 z = make_float2(0.f, 0.f);
    if (i != 0) {
      float2 F = s[PD(j2)];
      double b3t = (4.0 + 2.0 * cos(2.0 * M_PI * (double)j2 / 512.0)) / 6.0;
      double sc = dth * constv / (b3r * b3t) * (1.0 / (1024.0 * 512.0));
      z = make_float2((float)((double)F.x * sc), (float)((double)F.y * sc));
    }
    zetaT[(size_t)j2 * 1024 + p] = z;
  }
}

// ---------------- gather index map, ALL spans, natural theta order ----------------
__global__ __launch_bounds__(256) void k_idx_lp2c(int* __restrict__ idx1,
                                                  double d_rho, double aR) {
  int q = blockIdx.x * 256 + threadIdx.x;
  int span = q >> 19;                                // q / (NRHO*NTH)
  int ql = q & (NRHO * NTH - 1);
  int i = ql >> 9, j = ql & 511;
  const double beta = M_PI / 3.0;
  double d_th = 2.0 * beta / 512.0;
  double th = (double)(j - 256) * d_th;
  double er = exp((double)(i - 1024) * d_rho);
  double t1 = er * cos(th), t2 = er * sin(th);
  double a = (double)span * beta + beta / 2.0;
  double ca = cos(a), sa = sin(a);
  double l1 = ((t1 - (1.0 - aR)) * ca - t2 * sa) / aR;
  double l2 = -(((t1 - (1.0 - aR)) * sa + t2 * ca) / aR);
  l1 = (l1 + 1.0) / 2.0 * 511.0;
  l2 = (l2 + 1.0) / 2.0 * 511.0;
  double fy = floor(l1); fy = fy < 0.0 ? 0.0 : (fy > 510.0 ? 510.0 : fy);
  double fx = floor(l2); fx = fx < 0.0 ? 0.0 : (fx > 510.0 ? 510.0 : fx);
  idx1[q] = (int)fy * 512 + (int)fx;
}

// ---------------- gather + paired rfft(512): 8 rho-rows = 4 complex FFTs ----------------
// blockIdx.z = span. Thread tid: rho row r=tid>>5, 16 consecutive theta.
__global__ __launch_bounds__(256) void k_gather_rfft(const float* __restrict__ x,
                                                     const int* __restrict__ idx1,
                                                     const float2* __restrict__ tw1024f,
                                                     float2* __restrict__ T,
                                                     int b0, double d_rho) {
  __shared__ float2 s[4][S4];     // 16.6 KB
  __shared__ float2 twl[256];
  const int bx   = blockIdx.x;
  const int g    = ((bx & 7) << 4) | (bx >> 3);      // XCD ring swizzle (128 blocks)
  const int i0   = g * 8;
  const int lb   = blockIdx.y;
  const int span = blockIdx.z;
  const int tid  = threadIdx.x;
  twl[tid] = tw1024f[2 * tid];                       // exp(-2pi i m/512), m<256
  const int r  = tid >> 5;                           // rho row 0..7
  const int t5 = tid & 31;
  const float er = (float)exp((double)(i0 + r - 1024) * d_rho);
  const float* xb = x + (size_t)(b0 + lb) * (NIMG * NIMG);
  const int4* ip = (const int4*)(idx1 + span * (NRHO * NTH) + (i0 + r) * 512 + t5 * 16);
  int4 i4[4];
  #pragma unroll
  for (int u = 0; u < 4; ++u) i4[u] = ip[u];
  float v[16];
  #pragma unroll
  for (int u = 0; u < 4; ++u) {                      // 16 gathers issued back-to-back
    v[4 * u + 0] = xb[i4[u].x];
    v[4 * u + 1] = xb[i4[u].y];
    v[4 * u + 2] = xb[i4[u].z];
    v[4 * u + 3] = xb[i4[u].w];
  }
  float* sm = (float*)s[r >> 1];
  const int p = r & 1;
  #pragma unroll
  for (int u = 0; u < 16; ++u) {
    int j = t5 * 16 + u;
    int slot = __brev((unsigned)j) >> 23;            // bit-reversal for free
    sm[2 * SW(slot) + p] = v[u] * er;
  }
  // 4 complex FFT-512, radix-2 DIT (input bit-reversed, output natural)
  for (int lh = 0; lh < 9; ++lh) {
    __syncthreads();
    for (int it = 0; it < 4; ++it) {
      int e = tid + (it << 8);
      int m = e >> 8, b = e & 255;
      int pos = b & ((1 << lh) - 1);
      int ia  = ((b >> lh) << (lh + 1)) | pos;
      float2 w = twl[pos << (8 - lh)];
      float2* smm = s[m];
      float2 u = smm[SW(ia)];
      float2 vv = cmulf(smm[SW(ia + (1 << lh))], w);
      smm[SW(ia)]             = make_float2(u.x + vv.x, u.y + vv.y);
      smm[SW(ia + (1 << lh))] = make_float2(u.x - vv.x, u.y - vv.y);
    }
  }
  __syncthreads();
  // unpack pair spectra + transposed coalesced write (64B per theta bin)
  float2* Tb = T + (size_t)(span * gridDim.y + lb) * (ZROWS * NRHO);
  for (int it = 0; it < 8; ++it) {
    int e = tid + (it << 8);                         // 0..2047
    int k = e >> 3, rr = e & 7;
    int m = rr >> 1, pp = rr & 1;
    float2 Z  = s[m][SW(k)];
    float2 Zc = s[m][SW((512 - k) & 511)];
    float2 F;
    if (!pp) F = make_float2(0.5f * (Z.x + Zc.x), 0.5f * (Z.y - Zc.y));
    else     F = make_float2(0.5f * (Z.y + Zc.y), 0.5f * (Zc.x - Z.x));
    Tb[(size_t)k * NRHO + i0 + rr] = F;
  }
}

// ---------------- rho: fft1024 * zeta * ifft1024, radix-4, one theta-bin/block ----------------
// LDS indices pass through PD() pad-permutation: 4-way worst-case banks vs 16-way raw.
__global__ __launch_bounds__(256) void k_fft_rho(float2* __restrict__ T,
                                                 const float2* __restrict__ zetaT,
                                                 const float2* __restrict__ tw1024f) {
  __shared__ float2 s[1024 + 64];
  __shared__ float2 twl[1024 + 64];
  const int j    = blockIdx.x;
  const int lb   = blockIdx.y;
  const int span = blockIdx.z;
  const int tid  = threadIdx.x;
  for (int e = tid; e < 1024; e += 256) twl[PD(e)] = tw1024f[e];
  float2* row = T + ((size_t)(span * gridDim.y + lb) * ZROWS + j) * NRHO;
  {
    const float4* rp = (const float4*)row;
    for (int e = tid; e < 512; e += 256) {
      float4 v = rp[e];
      s[PD(2 * e)]     = make_float2(v.x, v.y);
      s[PD(2 * e + 1)] = make_float2(v.z, v.w);
    }
  }
  __syncthreads();
  #pragma unroll
  for (int lq = 8; lq >= 0; lq -= 2) {
    const int q = 1 << lq, tfac = 256 >> lq;
    int jj = tid & (q - 1);
    int base = ((tid >> lq) << (lq + 2)) | jj;
    float2 a = s[PD(base)], b = s[PD(base + q)];
    float2 c = s[PD(base + 2 * q)], d = s[PD(base + 3 * q)];
    float2 A = make_float2(a.x + c.x, a.y + c.y);
    float2 C = make_float2(a.x - c.x, a.y - c.y);
    float2 B = make_float2(b.x + d.x, b.y + d.y);
    float2 D = make_float2(b.x - d.x, b.y - d.y);
    float2 u0 = make_float2(A.x + B.x, A.y + B.y);
    float2 u2 = make_float2(A.x - B.x, A.y - B.y);
    float2 u1 = make_float2(C.x + D.y, C.y - D.x);
    float2 u3 = make_float2(C.x - D.y, C.y + D.x);
    int t1i = jj * tfac;
    s[PD(base)]         = u0;
    s[PD(base + q)]     = cmulf(u1, twl[PD(t1i)]);
    s[PD(base + 2 * q)] = cmulf(u2, twl[PD(2 * t1i)]);
    s[PD(base + 3 * q)] = cmulf(u3, twl[PD(3 * t1i)]);
    __syncthreads();
  }
  {
    const float2* zrow = zetaT + (size_t)j * NRHO;
    for (int e = tid; e < 1024; e += 256)
      s[PD(e)] = cmulf(s[PD(e)], zrow[e]);
  }
  __syncthreads();
  #pragma unroll
  for (int lq = 0; lq <= 8; lq += 2) {
    const int q = 1 << lq, tfac = 256 >> lq;
    int jj = tid & (q - 1);
    int base = ((tid >> lq) << (lq + 2)) | jj;
    int t1i = jj * tfac;
    float2 u0 = s[PD(base)];
    float2 u1 = cmulcf(s[PD(base + q)],     twl[PD(t1i)]);
    float2 u2 = cmulcf(s[PD(base + 2 * q)], twl[PD(2 * t1i)]);
    float2 u3 = cmulcf(s[PD(base + 3 * q)], twl[PD(3 * t1i)]);
    float2 t0 = make_float2(u0.x + u2.x, u0.y + u2.y);
    float2 t1 = make_float2(u0.x - u2.x, u0.y - u2.y);
    float2 t2 = make_float2(u1.x + u3.x, u1.y + u3.y);
    float2 t3 = make_float2(u1.x - u3.x, u1.y - u3.y);
    s[PD(base)]         = make_float2(t0.x + t2.x, t0.y + t2.y);
    s[PD(base + 2 * q)] = make_float2(t0.x - t2.x, t0.y - t2.y);
    s[PD(base + q)]     = make_float2(t1.x - t3.y, t1.y + t3.x);
    s[PD(base + 3 * q)] = make_float2(t1.x + t3.y, t1.y - t3.x);
    __syncthreads();
  }
  {
    float4* rp = (float4*)row;
    for (int e = tid; e < 512; e += 256) {
      float2 a = s[PD(2 * e)], b = s[PD(2 * e + 1)];
      rp[e] = make_float4(a.x, a.y, b.x, b.y);
    }
  }
}

// ---------------- paired Hermitian irfft(512): 8 rho-rows = 4 complex IFFTs ----------------
// Only theta rows 128..383 are ever sampled by the scatter -> write just those,
// COMPACTED (row j-128) and in natural theta order.
__global__ __launch_bounds__(256) void k_irfft_th(const float2* __restrict__ T,
                                                  const float2* __restrict__ tw1024f,
                                                  float* __restrict__ gkT) {
  __shared__ float2 s[4][S4];
  __shared__ float2 twl[256];
  const int i0   = blockIdx.x * 8;
  const int lb   = blockIdx.y;
  const int span = blockIdx.z;
  const int tid  = threadIdx.x;
  twl[tid] = tw1024f[2 * tid];
  const float2* Tb = T + (size_t)(span * gridDim.y + lb) * (ZROWS * NRHO);
  __syncthreads();
  // stage A: raw F -> LDS (pair m holds F0 at SW(k), F1 at SW(256+k))
  for (int it = 0; it < 8; ++it) {
    int e = tid + (it << 8);
    int k = e >> 3, rr = e & 7;
    int m = rr >> 1, p = rr & 1;
    s[m][SW(k + 256 * p)] = Tb[(size_t)k * NRHO + i0 + rr];
  }
  __syncthreads();
  // stage B: build Z = F0 + i*F1 over k=0..511 (registers to avoid in-place hazard)
  float2 Zr[8];
  for (int it = 0; it < 8; ++it) {
    int e = tid + (it << 8);
    int m = e >> 9, k = e & 511;
    float2 z;
    if (k == 256) z = make_float2(0.f, 0.f);
    else {
      int k2 = (k < 256) ? k : 512 - k;
      float2 F0 = s[m][SW(k2)];
      float2 F1 = s[m][SW(256 + k2)];
      if (k2 == 0) { F0.y = 0.f; F1.y = 0.f; }       // numpy irfft ignores DC imag
      if (k < 256) z = make_float2(F0.x - F1.y, F0.y + F1.x);
      else         z = make_float2(F0.x + F1.y, F1.x - F0.y);
    }
    Zr[it] = z;
  }
  __syncthreads();
  for (int it = 0; it < 8; ++it) {
    int e = tid + (it << 8);
    int m = e >> 9, k = e & 511;
    s[m][SW(k)] = Zr[it];
  }
  // inverse DIF (sign +): natural in -> bit-reversed out
  for (int lh = 8; lh >= 0; --lh) {
    __syncthreads();
    for (int it = 0; it < 4; ++it) {
      int e = tid + (it << 8);
      int m = e >> 8, b = e & 255;
      int pos = b & ((1 << lh) - 1);
      int ia  = ((b >> lh) << (lh + 1)) | pos;
      float2 w = twl[pos << (8 - lh)];
      float2* sm = s[m];
      float2 u = sm[SW(ia)];
      float2 v = sm[SW(ia + (1 << lh))];
      sm[SW(ia)] = make_float2(u.x + v.x, u.y + v.y);
      float2 d = make_float2(u.x - v.x, u.y - v.y);
      sm[SW(ia + (1 << lh))] = cmulcf(d, w);
    }
  }
  __syncthreads();
  // write ONLY theta rows 128..383, compacted+natural order (2048 values)
  float* gb = gkT + (size_t)(span * gridDim.y + lb) * (GROWS * NRHO);
  for (int it = 0; it < 8; ++it) {
    int e = tid + (it << 8);                         // 0..2047
    int ro = e >> 3, rr = e & 7;                     // ro = j-128
    int j = ro + 128;
    int jslot = __brev((unsigned)j) >> 23;           // DIF output slot of theta j
    float2 z = s[rr >> 1][SW(jslot)];
    gb[(size_t)ro * NRHO + i0 + rr] = (rr & 1) ? z.y : z.x;
  }
}

// ---------------- resample to (angle, det), ALL spans in one dispatch ----------------
// Span of angle t: k = (3t)>>10 (exact partition; boundaries never integral).
// gkT rows are compacted: row = fx - 128 (fx proven in [128,384)).
__global__ __launch_bounds__(256) void k_scatter(const float* __restrict__ gkT,
                                                 float* __restrict__ out,
                                                 int b0, int chunk,
                                                 double d_rho, double aR) {
  int p = blockIdx.x * 256 + threadIdx.x;
  if (p >= PTOT) return;
  const int t = p >> 9;
  const int d = p & 511;
  const int span = (3 * t) >> 10;
  const double beta = M_PI / 3.0;
  double th0 = (double)t * M_PI / 1024.0 - beta / 2.0;
  double th00 = th0 - (double)span * beta;
  double d_th = 2.0 * beta / 512.0;
  double th_lp0 = -256.0 * d_th, th_lpL = 255.0 * d_th;
  double p1 = (th00 - th_lp0) / (th_lpL - th_lp0) * 511.0;
  double s0v = (d == 511) ? 1.0 : (double)d * (2.0 / 511.0) - 1.0;
  double p2 = log(s0v * aR + (1.0 - aR) * cos(th00));
  double rho0 = -1024.0 * d_rho, rhoL = -1.0 * d_rho;
  p2 = (p2 - rho0) / (rhoL - rho0) * 1023.0;
  double fy = floor(p2); fy = fy < 0.0 ? 0.0 : (fy > 1022.0 ? 1022.0 : fy);
  double fx = floor(p1); fx = fx < 0.0 ? 0.0 : (fx > 510.0 ? 510.0 : fx);
  int idx = ((int)fx - 128) * 1024 + (int)fy;        // compacted natural-order row
  const float* gsp = gkT + (size_t)span * chunk * (GROWS * NRHO);
  for (int lb = 0; lb < chunk; ++lb)
    out[(size_t)(b0 + lb) * PTOT + p] = gsp[(size_t)lb * (GROWS * NRHO) + idx];
}

// ---------------- launch ----------------
extern "C" void kernel_launch(void* const* d_in, const int* in_sizes, int n_in,
                              void* d_out, int out_size, void* d_ws, size_t ws_size,
                              hipStream_t stream) {
  (void)n_in; (void)out_size;
  const float* x = (const float*)d_in[0];
  float* out = (float*)d_out;
  const int batch = in_sizes[0] / (NIMG * NIMG);

  const size_t zeta_b = (size_t)ZROWS * NRHO * sizeof(float2);          // 2 MB
  const size_t idx_b  = (size_t)NSPAN * NRHO * NTH * sizeof(int);       // 6 MB
  const size_t tab_b  = 2048 * sizeof(double) * 2 + 1024 * sizeof(float2) * 2;
  const size_t per_b  = (size_t)NSPAN * ((size_t)ZROWS * NRHO * sizeof(float2)
                      + (size_t)GROWS * NRHO * sizeof(float));          // 9 MB / image
  int chunk = batch;
  while (chunk > 1 && zeta_b + idx_b + tab_b + (size_t)chunk * per_b > ws_size) chunk >>= 1;

  char* ws = (char*)d_ws;
  float2* zetaT   = (float2*)ws;  ws += zeta_b;
  int*    idx1    = (int*)ws;     ws += idx_b;
  double* Ltab    = (double*)ws;  ws += 2048 * sizeof(double);
  double* amp     = (double*)ws;  ws += 2048 * sizeof(double);
  float2* tw1024f = (float2*)ws;  ws += 1024 * sizeof(float2);
  float2* tw2048f = (float2*)ws;  ws += 1024 * sizeof(float2);
  float2* T       = (float2*)ws;  ws += (size_t)NSPAN * chunk * ZROWS * NRHO * sizeof(float2);
  float*  gkT     = (float*)ws;

  k_pre     <<<dim3(8),    dim3(256), 0, stream>>>(Ltab, amp, tw1024f, tw2048f);
  k_zeta    <<<dim3(1024), dim3(256), 0, stream>>>(Ltab, amp, tw2048f, zetaT,
                                                   g_C.G_LA, g_C.dth, g_C.constv);
  k_idx_lp2c<<<dim3((NSPAN * NRHO * NTH) / 256), dim3(256), 0, stream>>>(idx1, g_C.d_rho, g_C.aR);

  for (int b0 = 0; b0 < batch; b0 += chunk) {
    int c = (b0 + chunk <= batch) ? chunk : (batch - b0);
    k_gather_rfft<<<dim3(NRHO / 8, c, NSPAN), dim3(256), 0, stream>>>(x, idx1, tw1024f, T, b0, g_C.d_rho);
    k_fft_rho    <<<dim3(ZROWS,   c, NSPAN), dim3(256), 0, stream>>>(T, zetaT, tw1024f);
    k_irfft_th   <<<dim3(NRHO / 8, c, NSPAN), dim3(256), 0, stream>>>(T, tw1024f, gkT);
    k_scatter    <<<dim3(PTOT / 256), dim3(256), 0, stream>>>(gkT, out, b0, c,
                                                              g_C.d_rho, g_C.aR);
  }
}